// Round 17
// baseline (1123.769 us; speedup 1.0000x reference)
//
#include <hip/hip_runtime.h>
#include <hip/hip_bf16.h>
#include <math.h>

#define S_   1000
#define B_   4
#define D_   1024
#define H_   16
#define HD_  64
#define L_   4
#define FF_  4096
#define N_   (S_*B_)   /* 4000 token rows */

typedef __bf16 bf16x8 __attribute__((ext_vector_type(8)));
typedef float  f32x4  __attribute__((ext_vector_type(4)));
typedef __attribute__((address_space(3))) unsigned short lds_u16;

__device__ __forceinline__ unsigned short f2b(float f) {
    unsigned u = __builtin_bit_cast(unsigned, f);
    u = (u + 0x7FFFu + ((u >> 16) & 1u)) >> 16;   // RNE
    return (unsigned short)u;
}
__device__ __forceinline__ float b2f(unsigned short s) {
    unsigned u = (unsigned)s << 16;
    return __builtin_bit_cast(float, u);
}

__device__ __forceinline__ void gl16(const void* g, void* l) {
    __builtin_amdgcn_global_load_lds(
        (const __attribute__((address_space(1))) unsigned int*)g,
        (__attribute__((address_space(3))) unsigned int*)l, 16, 0, 0);
}

// inline-asm LDS read: invisible to compiler's mem-dep model, so it cannot
// auto-insert vmcnt(0) between global_load_lds and this read.
__device__ __forceinline__ bf16x8 ldsr(unsigned addr) {
    bf16x8 r;
    asm volatile("ds_read_b128 %0, %1" : "=v"(r) : "v"(addr));
    return r;
}

// ---------------- embedding lookup ----------------
__global__ void embed_kernel(const int* __restrict__ tokens,
                             const float* __restrict__ emb,
                             float* __restrict__ x) {
    int n = blockIdx.x;
    int tok = tokens[n];
    const float4* src = (const float4*)(emb + (size_t)tok * D_);
    float4* dst = (float4*)(x + (size_t)n * D_);
    dst[threadIdx.x] = src[threadIdx.x];
}

// ---------------- weight fp32->bf16 conversion (one layer, 12M elems) ----------------
__global__ __launch_bounds__(256)
void cvtw_kernel(const float* __restrict__ wq, const float* __restrict__ wk,
                 const float* __restrict__ wv, const float* __restrict__ wo,
                 const float* __restrict__ w1, const float* __restrict__ w2,
                 unsigned short* __restrict__ dst) {
    const size_t M1 = (size_t)D_ * D_;
    const size_t M4 = (size_t)FF_ * D_;
    size_t i = ((size_t)blockIdx.x * 256 + threadIdx.x) * 4;
    const float* src; size_t off;
    if      (i < M1)        { src = wq; off = i; }
    else if (i < 2*M1)      { src = wk; off = i - M1; }
    else if (i < 3*M1)      { src = wv; off = i - 2*M1; }
    else if (i < 4*M1)      { src = wo; off = i - 3*M1; }
    else if (i < 4*M1+M4)   { src = w1; off = i - 4*M1; }
    else                    { src = w2; off = i - 4*M1 - M4; }
    float4 v = *(const float4*)(src + off);
    ushort4 u;
    u.x = f2b(v.x); u.y = f2b(v.y); u.z = f2b(v.z); u.w = f2b(v.w);
    *(ushort4*)(dst + i) = u;
}

// ---------------- layernorm: fp32 in, bf16 out ----------------
__global__ __launch_bounds__(256)
void ln_kernel(const float* __restrict__ in,
               const float* __restrict__ g,
               const float* __restrict__ b,
               unsigned short* __restrict__ out) {
    int n = blockIdx.x;
    int tid = threadIdx.x;
    const float4* row = (const float4*)(in + (size_t)n * D_);
    float4 v = row[tid];
    float s  = v.x + v.y + v.z + v.w;
    float sq = v.x*v.x + v.y*v.y + v.z*v.z + v.w*v.w;
    #pragma unroll
    for (int off = 32; off; off >>= 1) {
        s  += __shfl_down(s, off);
        sq += __shfl_down(sq, off);
    }
    __shared__ float rs[4], rq[4];
    int wid = tid >> 6;
    if ((tid & 63) == 0) { rs[wid] = s; rq[wid] = sq; }
    __syncthreads();
    s  = rs[0] + rs[1] + rs[2] + rs[3];
    sq = rq[0] + rq[1] + rq[2] + rq[3];
    float mean = s * (1.0f / D_);
    float var  = sq * (1.0f / D_) - mean * mean;
    float rstd = rsqrtf(var + 1e-5f);
    float4 gg = ((const float4*)g)[tid];
    float4 bb = ((const float4*)b)[tid];
    ushort4 o;
    o.x = f2b((v.x - mean) * rstd * gg.x + bb.x);
    o.y = f2b((v.y - mean) * rstd * gg.y + bb.y);
    o.z = f2b((v.z - mean) * rstd * gg.z + bb.z);
    o.w = f2b((v.w - mean) * rstd * gg.w + bb.w);
    ((ushort4*)(out + (size_t)n * D_))[tid] = o;
}

// ---------------- 256x64 asm-ds_read 2-phase GEMM, 512 thr, wave tile 32x64 ----------------
// (round-14 proven) QKV split + fused RoPE — o0/o1/o2 bf16 stride 1024, q *0.125
__global__ __launch_bounds__(512, 4)
void ggemm_kernel(const unsigned short* __restrict__ A,
                  const unsigned short* __restrict__ W,
                  const float* __restrict__ bb0, const float* __restrict__ bb1,
                  const float* __restrict__ bb2,
                  unsigned short* __restrict__ o0, unsigned short* __restrict__ o1,
                  unsigned short* __restrict__ o2,
                  int M, int K) {
    __shared__ __align__(16) unsigned short As[2][256 * 64];   // 64 KB
    __shared__ __align__(16) unsigned short Bs[2][64 * 64];    // 16 KB
    int tid = threadIdx.x;
    int w = tid >> 6, lane = tid & 63;
    int m0 = blockIdx.x * 256, e0 = blockIdx.y * 64;
    int l15 = lane & 15, l4 = lane >> 4, l7 = lane & 7;

    f32x4 acc[2][4] = {};

    auto stage = [&](int buf, int kt) {
        #pragma unroll
        for (int rep = 0; rep < 4; ++rep) {
            int slot = rep * 512 + tid;            // A: 256 rows x 8 chunks
            int r = slot >> 3, c = slot & 7;
            int ar = m0 + r; if (ar > M - 1) ar = M - 1;
            gl16(A + (size_t)ar * K + kt + (c ^ (r & 7)) * 8, &As[buf][slot * 8]);
        }
        {
            int slot = tid;                        // B: 64 rows x 8 chunks
            int r = slot >> 3, c = slot & 7;
            gl16(W + (size_t)(e0 + r) * K + kt + (c ^ (r & 7)) * 8, &Bs[buf][slot * 8]);
        }
    };

    int aoff[2], boff[4];
    #pragma unroll
    for (int i = 0; i < 2; ++i) aoff[i] = (w * 32 + i * 16 + l15) * 128;
    #pragma unroll
    for (int j = 0; j < 4; ++j) boff[j] = (j * 16 + l15) * 128;

    stage(0, 0);
    asm volatile("s_waitcnt vmcnt(0)" ::: "memory");
    __builtin_amdgcn_sched_barrier(0);
    __builtin_amdgcn_s_barrier();

    int nk = K >> 6;
    for (int t = 0; t < nk; ++t) {
        int cur = t & 1;
        if (t + 1 < nk) stage(cur ^ 1, (t + 1) << 6);
        __builtin_amdgcn_sched_barrier(0);
        unsigned aB = (unsigned)(size_t)(lds_u16*)&As[cur][0];
        unsigned bB = (unsigned)(size_t)(lds_u16*)&Bs[cur][0];
        #pragma unroll
        for (int ks = 0; ks < 2; ++ks) {
            unsigned soff = (unsigned)((((ks * 4) + l4) ^ l7) * 16);
            bf16x8 av[2], bv[4];
            #pragma unroll
            for (int i = 0; i < 2; ++i) av[i] = ldsr(aB + aoff[i] + soff);
            #pragma unroll
            for (int j = 0; j < 4; ++j) bv[j] = ldsr(bB + boff[j] + soff);
            asm volatile("s_waitcnt lgkmcnt(0)" ::: "memory");
            __builtin_amdgcn_sched_barrier(0);
            __builtin_amdgcn_s_setprio(1);
            #pragma unroll
            for (int i = 0; i < 2; ++i)
                #pragma unroll
                for (int j = 0; j < 4; ++j)
                    acc[i][j] = __builtin_amdgcn_mfma_f32_16x16x32_bf16(av[i], bv[j], acc[i][j], 0, 0, 0);
            __builtin_amdgcn_s_setprio(0);
        }
        asm volatile("s_waitcnt vmcnt(0)" ::: "memory");
        __builtin_amdgcn_sched_barrier(0);
        __builtin_amdgcn_s_barrier();
    }

    // ---- epilogue (C/D: col=lane&15, row=(lane>>4)*4+reg) ----
    int sel = e0 >> 10;                     // 64-tile never crosses 1024 boundary
    int eobase = e0 & 1023;
    const float* bp = (sel == 0) ? bb0 : (sel == 1) ? bb1 : bb2;
    unsigned short* op = (sel == 0) ? o0 : (sel == 1) ? o1 : o2;
    if (sel == 2) {
        #pragma unroll
        for (int i = 0; i < 2; ++i) {
            int mrow = m0 + w*32 + i*16 + l4*4;
            #pragma unroll
            for (int j = 0; j < 4; ++j) {
                int eo = eobase + j*16 + l15;
                float bval = bp[eo];
                #pragma unroll
                for (int r = 0; r < 4; ++r) {
                    int m = mrow + r;
                    if (m >= M) continue;
                    op[(size_t)m * 1024 + eo] = f2b(acc[i][j][r] + bval);
                }
            }
        }
    } else {
        // fused RoPE: pair (d, d+32) = acc[i][jj], acc[i][jj+2]; rotate on fp32
        float scale = (sel == 0) ? 0.125f : 1.0f;
        #pragma unroll
        for (int i = 0; i < 2; ++i) {
            int mrow = m0 + w*32 + i*16 + l4*4;
            #pragma unroll
            for (int jj = 0; jj < 2; ++jj) {
                int d5 = jj*16 + l15;                 // 0..31 within head
                int eo_a = eobase + d5;
                int eo_b = eo_a + 32;
                float ba = bp[eo_a], bbv = bp[eo_b];
                float invf = __expf(-(float)d5 * 0.2878231366242557f); // ln(1e4)/32
                #pragma unroll
                for (int r = 0; r < 4; ++r) {
                    int m = mrow + r;
                    if (m >= M) continue;
                    int s = m >> 2;                   // n = s*B + b, B=4
                    float ang = (float)s * invf;
                    float sn, cs;
                    __sincosf(ang, &sn, &cs);
                    float a = acc[i][jj][r]   + ba;
                    float c = acc[i][jj+2][r] + bbv;
                    op[(size_t)m * 1024 + eo_a] = f2b((a*cs - c*sn) * scale);
                    op[(size_t)m * 1024 + eo_b] = f2b((c*cs + a*sn) * scale);
                }
            }
        }
    }
}

// ---------------- 128x64 asm-ds_read 2-phase GEMM (best per-FLOP structure) ----------------
// 4 waves 2x2, wave tile 64x32, 48 KB LDS -> 3 blocks/CU.
// MODE 0: +residual — out fp32 stride 1024
// MODE 1: GELU — out bf16 stride FF_
template<int MODE>
__global__ __launch_bounds__(256, 2)
void dgemm_kernel(const unsigned short* __restrict__ A,
                  const unsigned short* __restrict__ W,
                  const float* __restrict__ bias,
                  const float* __restrict__ res,
                  void* __restrict__ outv,
                  int M, int K) {
    __shared__ __align__(16) unsigned short As[2][128 * 64];   // 32 KB
    __shared__ __align__(16) unsigned short Bs[2][64 * 64];    // 16 KB
    int tid = threadIdx.x;
    int w = tid >> 6, lane = tid & 63;
    int wr = w >> 1, wc = w & 1;
    int m0 = blockIdx.x * 128, e0 = blockIdx.y * 64;
    int l15 = lane & 15, l4 = lane >> 4, l7 = lane & 7;

    f32x4 acc[4][2] = {};

    auto stage = [&](int buf, int kt) {
        #pragma unroll
        for (int rep = 0; rep < 4; ++rep) {
            int slot = rep * 256 + tid;            // A: 128 rows
            int r = slot >> 3, c = slot & 7;
            int ar = m0 + r; if (ar > M - 1) ar = M - 1;
            gl16(A + (size_t)ar * K + kt + (c ^ (r & 7)) * 8, &As[buf][slot * 8]);
        }
        #pragma unroll
        for (int rep = 0; rep < 2; ++rep) {
            int slot = rep * 256 + tid;            // B: 64 rows
            int r = slot >> 3, c = slot & 7;
            gl16(W + (size_t)(e0 + r) * K + kt + (c ^ (r & 7)) * 8, &Bs[buf][slot * 8]);
        }
    };

    int aoff[4], boff[2];
    #pragma unroll
    for (int i = 0; i < 4; ++i) aoff[i] = (wr * 64 + i * 16 + l15) * 128;
    #pragma unroll
    for (int j = 0; j < 2; ++j) boff[j] = (wc * 32 + j * 16 + l15) * 128;

    stage(0, 0);
    asm volatile("s_waitcnt vmcnt(0)" ::: "memory");
    __builtin_amdgcn_sched_barrier(0);
    __builtin_amdgcn_s_barrier();

    int nk = K >> 6;
    for (int t = 0; t < nk; ++t) {
        int cur = t & 1;
        if (t + 1 < nk) stage(cur ^ 1, (t + 1) << 6);
        __builtin_amdgcn_sched_barrier(0);
        unsigned aB = (unsigned)(size_t)(lds_u16*)&As[cur][0];
        unsigned bB = (unsigned)(size_t)(lds_u16*)&Bs[cur][0];
        #pragma unroll
        for (int ks = 0; ks < 2; ++ks) {
            unsigned soff = (unsigned)((((ks * 4) + l4) ^ l7) * 16);
            bf16x8 av[4], bv[2];
            #pragma unroll
            for (int i = 0; i < 4; ++i) av[i] = ldsr(aB + aoff[i] + soff);
            #pragma unroll
            for (int j = 0; j < 2; ++j) bv[j] = ldsr(bB + boff[j] + soff);
            asm volatile("s_waitcnt lgkmcnt(0)" ::: "memory");
            __builtin_amdgcn_sched_barrier(0);
            __builtin_amdgcn_s_setprio(1);
            #pragma unroll
            for (int i = 0; i < 4; ++i)
                #pragma unroll
                for (int j = 0; j < 2; ++j)
                    acc[i][j] = __builtin_amdgcn_mfma_f32_16x16x32_bf16(av[i], bv[j], acc[i][j], 0, 0, 0);
            __builtin_amdgcn_s_setprio(0);
        }
        asm volatile("s_waitcnt vmcnt(0)" ::: "memory");
        __builtin_amdgcn_sched_barrier(0);
        __builtin_amdgcn_s_barrier();
    }

    if (MODE == 0) {
        float* out = (float*)outv;
        #pragma unroll
        for (int i = 0; i < 4; ++i) {
            int mrow = m0 + wr*64 + i*16 + l4*4;
            #pragma unroll
            for (int j = 0; j < 2; ++j) {
                int e = e0 + wc*32 + j*16 + l15;
                float bval = bias[e];
                #pragma unroll
                for (int r = 0; r < 4; ++r) {
                    int m = mrow + r;
                    if (m >= M) continue;
                    out[(size_t)m * 1024 + e] = acc[i][j][r] + bval + res[(size_t)m * 1024 + e];
                }
            }
        }
    } else {
        unsigned short* out = (unsigned short*)outv;
        #pragma unroll
        for (int i = 0; i < 4; ++i) {
            int mrow = m0 + wr*64 + i*16 + l4*4;
            #pragma unroll
            for (int j = 0; j < 2; ++j) {
                int e = e0 + wc*32 + j*16 + l15;
                float bval = bias[e];
                #pragma unroll
                for (int r = 0; r < 4; ++r) {
                    int m = mrow + r;
                    if (m >= M) continue;
                    float val = acc[i][j][r] + bval;
                    val = 0.5f * val * (1.0f + erff(val * 0.70710678118654752f));
                    out[(size_t)m * FF_ + e] = f2b(val);
                }
            }
        }
    }
}

// ---------------- fp32 tiled GEMM (final 64-col projection only) ----------------
__global__ __launch_bounds__(256)
void gemm_kernel(const float* __restrict__ A, const float* __restrict__ W,
                 const float* __restrict__ bias, float* __restrict__ C,
                 int M, int K, int E) {
    __shared__ float As[32][64];
    __shared__ float Ws[32][64];
    int tid = threadIdx.x;
    int m0 = blockIdx.x * 64, e0 = blockIdx.y * 64;
    int tx = tid & 15, ty = tid >> 4;
    int lrow = tid >> 2;
    int lkc  = (tid & 3) * 8;
    float acc[4][4] = {};
    const float* Arow = A + (size_t)(m0 + lrow) * K + lkc;
    const float* Wrow = W + (size_t)(e0 + lrow) * K + lkc;
    bool aval = (m0 + lrow) < M;

    for (int k0 = 0; k0 < K; k0 += 32) {
        float4 a0 = make_float4(0.f,0.f,0.f,0.f), a1 = a0;
        if (aval) {
            a0 = *(const float4*)(Arow + k0);
            a1 = *(const float4*)(Arow + k0 + 4);
        }
        float4 w0 = *(const float4*)(Wrow + k0);
        float4 w1 = *(const float4*)(Wrow + k0 + 4);
        As[lkc+0][lrow] = a0.x; As[lkc+1][lrow] = a0.y;
        As[lkc+2][lrow] = a0.z; As[lkc+3][lrow] = a0.w;
        As[lkc+4][lrow] = a1.x; As[lkc+5][lrow] = a1.y;
        As[lkc+6][lrow] = a1.z; As[lkc+7][lrow] = a1.w;
        Ws[lkc+0][lrow] = w0.x; Ws[lkc+1][lrow] = w0.y;
        Ws[lkc+2][lrow] = w0.z; Ws[lkc+3][lrow] = w0.w;
        Ws[lkc+4][lrow] = w1.x; Ws[lkc+5][lrow] = w1.y;
        Ws[lkc+6][lrow] = w1.z; Ws[lkc+7][lrow] = w1.w;
        __syncthreads();
        #pragma unroll
        for (int kk = 0; kk < 32; ++kk) {
            float4 a = *(const float4*)(&As[kk][ty*4]);
            float4 ww = *(const float4*)(&Ws[kk][tx*4]);
            acc[0][0] += a.x*ww.x; acc[0][1] += a.x*ww.y; acc[0][2] += a.x*ww.z; acc[0][3] += a.x*ww.w;
            acc[1][0] += a.y*ww.x; acc[1][1] += a.y*ww.y; acc[1][2] += a.y*ww.z; acc[1][3] += a.y*ww.w;
            acc[2][0] += a.z*ww.x; acc[2][1] += a.z*ww.y; acc[2][2] += a.z*ww.z; acc[2][3] += a.z*ww.w;
            acc[3][0] += a.w*ww.x; acc[3][1] += a.w*ww.y; acc[3][2] += a.w*ww.z; acc[3][3] += a.w*ww.w;
        }
        __syncthreads();
    }
    #pragma unroll
    for (int i = 0; i < 4; ++i) {
        int m = m0 + ty*4 + i;
        if (m >= M) continue;
        #pragma unroll
        for (int j = 0; j < 4; ++j) {
            int e = e0 + tx*4 + j;
            C[(size_t)m * E + e] = acc[i][j] + bias[e];
        }
    }
}

// ---------------- V transpose: [s][b][h*64+d] bf16 -> [bh][d][1024] bf16 ----------------
__global__ __launch_bounds__(256)
void vtr_kernel(const unsigned short* __restrict__ vin,
                unsigned short* __restrict__ vout) {
    __shared__ unsigned short T[64][65];
    int tt = blockIdx.x;
    int bh = blockIdx.y;
    int b = bh >> 4, h = bh & 15;
    int tid = threadIdx.x;
    #pragma unroll
    for (int rep = 0; rep < 2; ++rep) {
        int slot = rep * 256 + tid;
        int r = slot >> 3, ch = slot & 7;
        int t = tt * 64 + r;
        unsigned short e[8] = {0,0,0,0,0,0,0,0};
        if (t < S_) {
            const unsigned short* src = vin + ((size_t)t * B_ + b) * D_ + h * HD_ + ch * 8;
            *(ushort4*)&e[0] = *(const ushort4*)(src);
            *(ushort4*)&e[4] = *(const ushort4*)(src + 4);
        }
        #pragma unroll
        for (int u = 0; u < 8; ++u) T[r][ch*8+u] = e[u];
    }
    __syncthreads();
    #pragma unroll
    for (int rep = 0; rep < 2; ++rep) {
        int slot = rep * 256 + tid;
        int d = slot >> 3, ch = slot & 7;
        unsigned short e[8];
        #pragma unroll
        for (int u = 0; u < 8; ++u) e[u] = T[ch*8+u][d];
        unsigned short* dst = vout + ((size_t)bh * 64 + d) * 1024 + tt * 64 + ch * 8;
        *(ushort4*)(dst)     = *(ushort4*)&e[0];
        *(ushort4*)(dst + 4) = *(ushort4*)&e[4];
    }
}

// ---------------- bf16 MFMA flash attention (64 q x (b,h), round-13 proven) ----------------
__global__ __launch_bounds__(256)
void mattn_kernel(const unsigned short* __restrict__ qg,
                  const unsigned short* __restrict__ kg,
                  const unsigned short* __restrict__ vt,
                  unsigned short* __restrict__ o) {
    __shared__ __align__(16) unsigned short Ks[64 * 64];
    __shared__ __align__(16) unsigned short Vs[64 * 64];
    __shared__ __align__(16) unsigned short Ps[4][16 * 64];

    int bid = blockIdx.x;
    int qt = bid & 15;
    int bh = bid >> 4;
    int b = bh >> 4, h = bh & 15;
    int tid = threadIdx.x;
    int w = tid >> 6, lane = tid & 63;
    int l15 = lane & 15, l4 = lane >> 4, l7 = lane & 7;
    int q0 = qt * 64 + w * 16;

    int srow = lane >> 3;
    int schunk = ((lane & 7) ^ srow) * 8;

    bf16x8 qfr[2];
    {
        int qr = q0 + l15; if (qr > S_ - 1) qr = S_ - 1;
        const unsigned short* qrow = qg + ((size_t)qr * B_ + b) * D_ + h * HD_;
        qfr[0] = *(const bf16x8*)(qrow + l4 * 8);
        qfr[1] = *(const bf16x8*)(qrow + 32 + l4 * 8);
    }

    f32x4 accO[4] = {};
    float mreg[4] = {-1e30f, -1e30f, -1e30f, -1e30f};
    float lreg[4] = {0.f, 0.f, 0.f, 0.f};

    for (int t0 = 0; t0 < 1024; t0 += 64) {
        __syncthreads();
        #pragma unroll
        for (int c = 0; c < 2; ++c) {
            int r0 = w * 16 + c * 8;
            int tr = t0 + r0 + srow; if (tr > S_ - 1) tr = S_ - 1;
            gl16(kg + ((size_t)tr * B_ + b) * D_ + h * HD_ + schunk, &Ks[r0 * 64]);
            gl16(vt + ((size_t)bh * 64 + r0 + srow) * 1024 + t0 + schunk, &Vs[r0 * 64]);
        }
        __syncthreads();

        f32x4 s[4] = {};
        #pragma unroll
        for (int ks = 0; ks < 2; ++ks) {
            int cc = ks * 4 + l4;
            int slot = (cc ^ l7) * 16;
            #pragma unroll
            for (int j = 0; j < 4; ++j) {
                bf16x8 kf = *(const bf16x8*)((const char*)Ks + (j*16 + l15) * 128 + slot);
                s[j] = __builtin_amdgcn_mfma_f32_16x16x32_bf16(qfr[ks], kf, s[j], 0, 0, 0);
            }
        }
        #pragma unroll
        for (int j = 0; j < 4; ++j) {
            int t = t0 + j * 16 + l15;
            if (t >= S_) { s[j][0] = -1e30f; s[j][1] = -1e30f; s[j][2] = -1e30f; s[j][3] = -1e30f; }
        }
        float rm[4], sc[4], rsum[4];
        #pragma unroll
        for (int r = 0; r < 4; ++r)
            rm[r] = fmaxf(fmaxf(s[0][r], s[1][r]), fmaxf(s[2][r], s[3][r]));
        #pragma unroll
        for (int mk = 1; mk <= 8; mk <<= 1) {
            #pragma unroll
            for (int r = 0; r < 4; ++r) rm[r] = fmaxf(rm[r], __shfl_xor(rm[r], mk));
        }
        #pragma unroll
        for (int r = 0; r < 4; ++r) {
            float mn = fmaxf(mreg[r], rm[r]);
            sc[r] = __expf(mreg[r] - mn);
            mreg[r] = mn;
            rsum[r] = 0.f;
        }
        #pragma unroll
        for (int j = 0; j < 4; ++j) {
            int inb = (j * 16 + l15) * 2;
            #pragma unroll
            for (int r = 0; r < 4; ++r) {
                float p = __expf(s[j][r] - mreg[r]);
                rsum[r] += p;
                int row = l4 * 4 + r;
                *(unsigned short*)((char*)&Ps[w][0] + row * 128 +
                    ((((inb >> 4) ^ (row & 7)) << 4)) + (inb & 15)) = f2b(p);
            }
        }
        #pragma unroll
        for (int mk = 1; mk <= 8; mk <<= 1) {
            #pragma unroll
            for (int r = 0; r < 4; ++r) rsum[r] += __shfl_xor(rsum[r], mk);
        }
        #pragma unroll
        for (int r = 0; r < 4; ++r) lreg[r] = lreg[r] * sc[r] + rsum[r];
        #pragma unroll
        for (int j = 0; j < 4; ++j) {
            accO[j][0] *= sc[0]; accO[j][1] *= sc[1];
            accO[j][2] *= sc[2]; accO[j][3] *= sc[3];
        }
        #pragma unroll
        for (int ks = 0; ks < 2; ++ks) {
            int cc = ks * 4 + l4;
            int slot = (cc ^ l7) * 16;
            bf16x8 pf = *(const bf16x8*)((const char*)&Ps[w][0] + l15 * 128 + slot);
            #pragma unroll
            for (int j = 0; j < 4; ++j) {
                bf16x8 vf = *(const bf16x8*)((const char*)Vs + (j*16 + l15) * 128 + slot);
                accO[j] = __builtin_amdgcn_mfma_f32_16x16x32_bf16(pf, vf, accO[j], 0, 0, 0);
            }
        }
    }
    #pragma unroll
    for (int r = 0; r < 4; ++r) {
        int q = q0 + l4 * 4 + r;
        if (q >= S_) continue;
        float inv = 1.0f / lreg[r];
        unsigned short* orow = o + ((size_t)q * B_ + b) * D_ + h * HD_;
        #pragma unroll
        for (int j = 0; j < 4; ++j)
            orow[j * 16 + l15] = f2b(accO[j][r] * inv);
    }
}

extern "C" void kernel_launch(void* const* d_in, const int* in_sizes, int n_in,
                              void* d_out, int out_size, void* d_ws, size_t ws_size,
                              hipStream_t stream) {
    const int*   tokens = (const int*)  d_in[0];
    const float* Wemb   = (const float*)d_in[1];
    const float* Wq     = (const float*)d_in[2];
    const float* bq     = (const float*)d_in[3];
    const float* Wk     = (const float*)d_in[4];
    const float* bk     = (const float*)d_in[5];
    const float* Wv     = (const float*)d_in[6];
    const float* bv     = (const float*)d_in[7];
    const float* Wo     = (const float*)d_in[8];
    const float* bo     = (const float*)d_in[9];
    const float* ln1g   = (const float*)d_in[10];
    const float* ln1b   = (const float*)d_in[11];
    const float* ln2g   = (const float*)d_in[12];
    const float* ln2b   = (const float*)d_in[13];
    const float* W1     = (const float*)d_in[14];
    const float* b1     = (const float*)d_in[15];
    const float* W2     = (const float*)d_in[16];
    const float* b2     = (const float*)d_in[17];
    const float* Wout   = (const float*)d_in[18];
    const float* bout   = (const float*)d_in[19];
    float* out = (float*)d_out;

    const size_t ND = (size_t)N_ * D_;
    const size_t NF = (size_t)N_ * FF_;
    const size_t M1 = (size_t)D_ * D_;
    const size_t M4 = (size_t)FF_ * D_;
    const size_t VT = (size_t)64 * 64 * 1024;

    float* x  = (float*)d_ws;
    unsigned short* hb = (unsigned short*)(x + ND);
    unsigned short* qb = hb + ND;
    unsigned short* kb = qb + ND;
    unsigned short* vb = kb + ND;
    unsigned short* ob = vb + ND;
    unsigned short* vt = ob + ND;
    unsigned short* f1 = vt + VT;
    unsigned short* wb = f1 + NF;           // 12M bf16 per-layer weights

    dim3 blk(256);
    embed_kernel<<<N_, blk, 0, stream>>>(tokens, Wemb, x);

    dim3 gQKV(16, 48);   // 256x64 tiles: M=4000->16, E=3072->48 (768 blocks)
    dim3 gW1(32, 64);    // 128x64 tiles: E=4096->64 (2048 blocks)
    dim3 gE64(32, 16);   // 128x64 tiles, E=1024->16 (512 blocks)
    dim3 gCv(12288);
    dim3 gVt(16, 64);
    dim3 gAt(16 * 64);   // 16 q-tiles of 64 x 64 (b,h)
    dim3 gOut((N_ + 63) / 64, 1);

    for (int l = 0; l < L_; ++l) {
        cvtw_kernel<<<gCv, blk, 0, stream>>>(Wq + l*M1, Wk + l*M1, Wv + l*M1,
                                             Wo + l*M1, W1 + l*M4, W2 + l*M4, wb);
        ln_kernel<<<N_, blk, 0, stream>>>(x, ln1g + l*D_, ln1b + l*D_, hb);
        ggemm_kernel<<<gQKV, dim3(512), 0, stream>>>(hb, wb,
            bq + l*D_, bk + l*D_, bv + l*D_, qb, kb, vb, N_, D_);
        vtr_kernel<<<gVt, blk, 0, stream>>>(vb, vt);
        mattn_kernel<<<gAt, blk, 0, stream>>>(qb, kb, vt, ob);
        dgemm_kernel<0><<<gE64, blk, 0, stream>>>(ob, wb + 3*M1,
            bo + l*D_, x, x, N_, D_);
        ln_kernel<<<N_, blk, 0, stream>>>(x, ln2g + l*D_, ln2b + l*D_, hb);
        dgemm_kernel<1><<<gW1, blk, 0, stream>>>(hb, wb + 4*M1,
            b1 + l*FF_, nullptr, f1, N_, D_);
        dgemm_kernel<0><<<gE64, blk, 0, stream>>>(f1, wb + 4*M1 + M4,
            b2 + l*D_, x, x, N_, FF_);
    }
    gemm_kernel<<<gOut, blk, 0, stream>>>(x, Wout, bout, out, N_, D_, 64);
}

// Round 18
// 1118.269 us; speedup vs baseline: 1.0049x; 1.0049x over previous
//
#include <hip/hip_runtime.h>
#include <hip/hip_bf16.h>
#include <math.h>

#define S_   1000
#define B_   4
#define D_   1024
#define H_   16
#define HD_  64
#define L_   4
#define FF_  4096
#define N_   (S_*B_)   /* 4000 token rows */

typedef __bf16 bf16x8 __attribute__((ext_vector_type(8)));
typedef float  f32x4  __attribute__((ext_vector_type(4)));
typedef __attribute__((address_space(3))) unsigned short lds_u16;

__device__ __forceinline__ unsigned short f2b(float f) {
    unsigned u = __builtin_bit_cast(unsigned, f);
    u = (u + 0x7FFFu + ((u >> 16) & 1u)) >> 16;   // RNE
    return (unsigned short)u;
}
__device__ __forceinline__ float b2f(unsigned short s) {
    unsigned u = (unsigned)s << 16;
    return __builtin_bit_cast(float, u);
}

__device__ __forceinline__ void gl16(const void* g, void* l) {
    __builtin_amdgcn_global_load_lds(
        (const __attribute__((address_space(1))) unsigned int*)g,
        (__attribute__((address_space(3))) unsigned int*)l, 16, 0, 0);
}

// inline-asm LDS read: invisible to compiler's mem-dep model, so it cannot
// auto-insert vmcnt(0) between global_load_lds and this read.
__device__ __forceinline__ bf16x8 ldsr(unsigned addr) {
    bf16x8 r;
    asm volatile("ds_read_b128 %0, %1" : "=v"(r) : "v"(addr));
    return r;
}

// ---------------- embedding lookup ----------------
__global__ void embed_kernel(const int* __restrict__ tokens,
                             const float* __restrict__ emb,
                             float* __restrict__ x) {
    int n = blockIdx.x;
    int tok = tokens[n];
    const float4* src = (const float4*)(emb + (size_t)tok * D_);
    float4* dst = (float4*)(x + (size_t)n * D_);
    dst[threadIdx.x] = src[threadIdx.x];
}

// ---------------- weight fp32->bf16 conversion (one layer, 12M elems) ----------------
__global__ __launch_bounds__(256)
void cvtw_kernel(const float* __restrict__ wq, const float* __restrict__ wk,
                 const float* __restrict__ wv, const float* __restrict__ wo,
                 const float* __restrict__ w1, const float* __restrict__ w2,
                 unsigned short* __restrict__ dst) {
    const size_t M1 = (size_t)D_ * D_;
    const size_t M4 = (size_t)FF_ * D_;
    size_t i = ((size_t)blockIdx.x * 256 + threadIdx.x) * 4;
    const float* src; size_t off;
    if      (i < M1)        { src = wq; off = i; }
    else if (i < 2*M1)      { src = wk; off = i - M1; }
    else if (i < 3*M1)      { src = wv; off = i - 2*M1; }
    else if (i < 4*M1)      { src = wo; off = i - 3*M1; }
    else if (i < 4*M1+M4)   { src = w1; off = i - 4*M1; }
    else                    { src = w2; off = i - 4*M1 - M4; }
    float4 v = *(const float4*)(src + off);
    ushort4 u;
    u.x = f2b(v.x); u.y = f2b(v.y); u.z = f2b(v.z); u.w = f2b(v.w);
    *(ushort4*)(dst + i) = u;
}

// ---------------- layernorm: fp32 in, bf16 out ----------------
__global__ __launch_bounds__(256)
void ln_kernel(const float* __restrict__ in,
               const float* __restrict__ g,
               const float* __restrict__ b,
               unsigned short* __restrict__ out) {
    int n = blockIdx.x;
    int tid = threadIdx.x;
    const float4* row = (const float4*)(in + (size_t)n * D_);
    float4 v = row[tid];
    float s  = v.x + v.y + v.z + v.w;
    float sq = v.x*v.x + v.y*v.y + v.z*v.z + v.w*v.w;
    #pragma unroll
    for (int off = 32; off; off >>= 1) {
        s  += __shfl_down(s, off);
        sq += __shfl_down(sq, off);
    }
    __shared__ float rs[4], rq[4];
    int wid = tid >> 6;
    if ((tid & 63) == 0) { rs[wid] = s; rq[wid] = sq; }
    __syncthreads();
    s  = rs[0] + rs[1] + rs[2] + rs[3];
    sq = rq[0] + rq[1] + rq[2] + rq[3];
    float mean = s * (1.0f / D_);
    float var  = sq * (1.0f / D_) - mean * mean;
    float rstd = rsqrtf(var + 1e-5f);
    float4 gg = ((const float4*)g)[tid];
    float4 bb = ((const float4*)b)[tid];
    ushort4 o;
    o.x = f2b((v.x - mean) * rstd * gg.x + bb.x);
    o.y = f2b((v.y - mean) * rstd * gg.y + bb.y);
    o.z = f2b((v.z - mean) * rstd * gg.z + bb.z);
    o.w = f2b((v.w - mean) * rstd * gg.w + bb.w);
    ((ushort4*)(out + (size_t)n * D_))[tid] = o;
}

// ---------------- 256x64 asm-ds_read 2-phase GEMM, 512 thr, wave tile 32x64 ----------------
// (round-14 proven) QKV split + fused RoPE — o0/o1/o2 bf16 stride 1024, q *0.125
__global__ __launch_bounds__(512, 4)
void ggemm_kernel(const unsigned short* __restrict__ A,
                  const unsigned short* __restrict__ W,
                  const float* __restrict__ bb0, const float* __restrict__ bb1,
                  const float* __restrict__ bb2,
                  unsigned short* __restrict__ o0, unsigned short* __restrict__ o1,
                  unsigned short* __restrict__ o2,
                  int M, int K) {
    __shared__ __align__(16) unsigned short As[2][256 * 64];   // 64 KB
    __shared__ __align__(16) unsigned short Bs[2][64 * 64];    // 16 KB
    int tid = threadIdx.x;
    int w = tid >> 6, lane = tid & 63;
    int m0 = blockIdx.x * 256, e0 = blockIdx.y * 64;
    int l15 = lane & 15, l4 = lane >> 4, l7 = lane & 7;

    f32x4 acc[2][4] = {};

    auto stage = [&](int buf, int kt) {
        #pragma unroll
        for (int rep = 0; rep < 4; ++rep) {
            int slot = rep * 512 + tid;            // A: 256 rows x 8 chunks
            int r = slot >> 3, c = slot & 7;
            int ar = m0 + r; if (ar > M - 1) ar = M - 1;
            gl16(A + (size_t)ar * K + kt + (c ^ (r & 7)) * 8, &As[buf][slot * 8]);
        }
        {
            int slot = tid;                        // B: 64 rows x 8 chunks
            int r = slot >> 3, c = slot & 7;
            gl16(W + (size_t)(e0 + r) * K + kt + (c ^ (r & 7)) * 8, &Bs[buf][slot * 8]);
        }
    };

    int aoff[2], boff[4];
    #pragma unroll
    for (int i = 0; i < 2; ++i) aoff[i] = (w * 32 + i * 16 + l15) * 128;
    #pragma unroll
    for (int j = 0; j < 4; ++j) boff[j] = (j * 16 + l15) * 128;

    stage(0, 0);
    asm volatile("s_waitcnt vmcnt(0)" ::: "memory");
    __builtin_amdgcn_sched_barrier(0);
    __builtin_amdgcn_s_barrier();

    int nk = K >> 6;
    for (int t = 0; t < nk; ++t) {
        int cur = t & 1;
        if (t + 1 < nk) stage(cur ^ 1, (t + 1) << 6);
        __builtin_amdgcn_sched_barrier(0);
        unsigned aB = (unsigned)(size_t)(lds_u16*)&As[cur][0];
        unsigned bB = (unsigned)(size_t)(lds_u16*)&Bs[cur][0];
        #pragma unroll
        for (int ks = 0; ks < 2; ++ks) {
            unsigned soff = (unsigned)((((ks * 4) + l4) ^ l7) * 16);
            bf16x8 av[2], bv[4];
            #pragma unroll
            for (int i = 0; i < 2; ++i) av[i] = ldsr(aB + aoff[i] + soff);
            #pragma unroll
            for (int j = 0; j < 4; ++j) bv[j] = ldsr(bB + boff[j] + soff);
            asm volatile("s_waitcnt lgkmcnt(0)" ::: "memory");
            __builtin_amdgcn_sched_barrier(0);
            __builtin_amdgcn_s_setprio(1);
            #pragma unroll
            for (int i = 0; i < 2; ++i)
                #pragma unroll
                for (int j = 0; j < 4; ++j)
                    acc[i][j] = __builtin_amdgcn_mfma_f32_16x16x32_bf16(av[i], bv[j], acc[i][j], 0, 0, 0);
            __builtin_amdgcn_s_setprio(0);
        }
        asm volatile("s_waitcnt vmcnt(0)" ::: "memory");
        __builtin_amdgcn_sched_barrier(0);
        __builtin_amdgcn_s_barrier();
    }

    // ---- epilogue (C/D: col=lane&15, row=(lane>>4)*4+reg) ----
    int sel = e0 >> 10;                     // 64-tile never crosses 1024 boundary
    int eobase = e0 & 1023;
    const float* bp = (sel == 0) ? bb0 : (sel == 1) ? bb1 : bb2;
    unsigned short* op = (sel == 0) ? o0 : (sel == 1) ? o1 : o2;
    if (sel == 2) {
        #pragma unroll
        for (int i = 0; i < 2; ++i) {
            int mrow = m0 + w*32 + i*16 + l4*4;
            #pragma unroll
            for (int j = 0; j < 4; ++j) {
                int eo = eobase + j*16 + l15;
                float bval = bp[eo];
                #pragma unroll
                for (int r = 0; r < 4; ++r) {
                    int m = mrow + r;
                    if (m >= M) continue;
                    op[(size_t)m * 1024 + eo] = f2b(acc[i][j][r] + bval);
                }
            }
        }
    } else {
        // fused RoPE: pair (d, d+32) = acc[i][jj], acc[i][jj+2]; rotate on fp32
        float scale = (sel == 0) ? 0.125f : 1.0f;
        #pragma unroll
        for (int i = 0; i < 2; ++i) {
            int mrow = m0 + w*32 + i*16 + l4*4;
            #pragma unroll
            for (int jj = 0; jj < 2; ++jj) {
                int d5 = jj*16 + l15;                 // 0..31 within head
                int eo_a = eobase + d5;
                int eo_b = eo_a + 32;
                float ba = bp[eo_a], bbv = bp[eo_b];
                float invf = __expf(-(float)d5 * 0.2878231366242557f); // ln(1e4)/32
                #pragma unroll
                for (int r = 0; r < 4; ++r) {
                    int m = mrow + r;
                    if (m >= M) continue;
                    int s = m >> 2;                   // n = s*B + b, B=4
                    float ang = (float)s * invf;
                    float sn, cs;
                    __sincosf(ang, &sn, &cs);
                    float a = acc[i][jj][r]   + ba;
                    float c = acc[i][jj+2][r] + bbv;
                    op[(size_t)m * 1024 + eo_a] = f2b((a*cs - c*sn) * scale);
                    op[(size_t)m * 1024 + eo_b] = f2b((c*cs + a*sn) * scale);
                }
            }
        }
    }
}

// ---------------- 128x64 asm-ds_read 2-phase GEMM (best per-FLOP structure) ----------------
// 4 waves 2x2, wave tile 64x32, 48 KB LDS -> 3 blocks/CU.
// MODE 0: +residual — out fp32 stride 1024
// MODE 1: GELU — out bf16 stride FF_
template<int MODE>
__global__ __launch_bounds__(256, 2)
void dgemm_kernel(const unsigned short* __restrict__ A,
                  const unsigned short* __restrict__ W,
                  const float* __restrict__ bias,
                  const float* __restrict__ res,
                  void* __restrict__ outv,
                  int M, int K) {
    __shared__ __align__(16) unsigned short As[2][128 * 64];   // 32 KB
    __shared__ __align__(16) unsigned short Bs[2][64 * 64];    // 16 KB
    int tid = threadIdx.x;
    int w = tid >> 6, lane = tid & 63;
    int wr = w >> 1, wc = w & 1;
    int m0 = blockIdx.x * 128, e0 = blockIdx.y * 64;
    int l15 = lane & 15, l4 = lane >> 4, l7 = lane & 7;

    f32x4 acc[4][2] = {};

    auto stage = [&](int buf, int kt) {
        #pragma unroll
        for (int rep = 0; rep < 4; ++rep) {
            int slot = rep * 256 + tid;            // A: 128 rows
            int r = slot >> 3, c = slot & 7;
            int ar = m0 + r; if (ar > M - 1) ar = M - 1;
            gl16(A + (size_t)ar * K + kt + (c ^ (r & 7)) * 8, &As[buf][slot * 8]);
        }
        #pragma unroll
        for (int rep = 0; rep < 2; ++rep) {
            int slot = rep * 256 + tid;            // B: 64 rows
            int r = slot >> 3, c = slot & 7;
            gl16(W + (size_t)(e0 + r) * K + kt + (c ^ (r & 7)) * 8, &Bs[buf][slot * 8]);
        }
    };

    int aoff[4], boff[2];
    #pragma unroll
    for (int i = 0; i < 4; ++i) aoff[i] = (wr * 64 + i * 16 + l15) * 128;
    #pragma unroll
    for (int j = 0; j < 2; ++j) boff[j] = (wc * 32 + j * 16 + l15) * 128;

    stage(0, 0);
    asm volatile("s_waitcnt vmcnt(0)" ::: "memory");
    __builtin_amdgcn_sched_barrier(0);
    __builtin_amdgcn_s_barrier();

    int nk = K >> 6;
    for (int t = 0; t < nk; ++t) {
        int cur = t & 1;
        if (t + 1 < nk) stage(cur ^ 1, (t + 1) << 6);
        __builtin_amdgcn_sched_barrier(0);
        unsigned aB = (unsigned)(size_t)(lds_u16*)&As[cur][0];
        unsigned bB = (unsigned)(size_t)(lds_u16*)&Bs[cur][0];
        #pragma unroll
        for (int ks = 0; ks < 2; ++ks) {
            unsigned soff = (unsigned)((((ks * 4) + l4) ^ l7) * 16);
            bf16x8 av[4], bv[2];
            #pragma unroll
            for (int i = 0; i < 4; ++i) av[i] = ldsr(aB + aoff[i] + soff);
            #pragma unroll
            for (int j = 0; j < 2; ++j) bv[j] = ldsr(bB + boff[j] + soff);
            asm volatile("s_waitcnt lgkmcnt(0)" ::: "memory");
            __builtin_amdgcn_sched_barrier(0);
            __builtin_amdgcn_s_setprio(1);
            #pragma unroll
            for (int i = 0; i < 4; ++i)
                #pragma unroll
                for (int j = 0; j < 2; ++j)
                    acc[i][j] = __builtin_amdgcn_mfma_f32_16x16x32_bf16(av[i], bv[j], acc[i][j], 0, 0, 0);
            __builtin_amdgcn_s_setprio(0);
        }
        asm volatile("s_waitcnt vmcnt(0)" ::: "memory");
        __builtin_amdgcn_sched_barrier(0);
        __builtin_amdgcn_s_barrier();
    }

    if (MODE == 0) {
        float* out = (float*)outv;
        #pragma unroll
        for (int i = 0; i < 4; ++i) {
            int mrow = m0 + wr*64 + i*16 + l4*4;
            #pragma unroll
            for (int j = 0; j < 2; ++j) {
                int e = e0 + wc*32 + j*16 + l15;
                float bval = bias[e];
                #pragma unroll
                for (int r = 0; r < 4; ++r) {
                    int m = mrow + r;
                    if (m >= M) continue;
                    out[(size_t)m * 1024 + e] = acc[i][j][r] + bval + res[(size_t)m * 1024 + e];
                }
            }
        }
    } else {
        unsigned short* out = (unsigned short*)outv;
        #pragma unroll
        for (int i = 0; i < 4; ++i) {
            int mrow = m0 + wr*64 + i*16 + l4*4;
            #pragma unroll
            for (int j = 0; j < 2; ++j) {
                int e = e0 + wc*32 + j*16 + l15;
                float bval = bias[e];
                #pragma unroll
                for (int r = 0; r < 4; ++r) {
                    int m = mrow + r;
                    if (m >= M) continue;
                    float val = acc[i][j][r] + bval;
                    val = 0.5f * val * (1.0f + erff(val * 0.70710678118654752f));
                    out[(size_t)m * FF_ + e] = f2b(val);
                }
            }
        }
    }
}

// ---------------- fp32 tiled GEMM (final 64-col projection only) ----------------
__global__ __launch_bounds__(256)
void gemm_kernel(const float* __restrict__ A, const float* __restrict__ W,
                 const float* __restrict__ bias, float* __restrict__ C,
                 int M, int K, int E) {
    __shared__ float As[32][64];
    __shared__ float Ws[32][64];
    int tid = threadIdx.x;
    int m0 = blockIdx.x * 64, e0 = blockIdx.y * 64;
    int tx = tid & 15, ty = tid >> 4;
    int lrow = tid >> 2;
    int lkc  = (tid & 3) * 8;
    float acc[4][4] = {};
    const float* Arow = A + (size_t)(m0 + lrow) * K + lkc;
    const float* Wrow = W + (size_t)(e0 + lrow) * K + lkc;
    bool aval = (m0 + lrow) < M;

    for (int k0 = 0; k0 < K; k0 += 32) {
        float4 a0 = make_float4(0.f,0.f,0.f,0.f), a1 = a0;
        if (aval) {
            a0 = *(const float4*)(Arow + k0);
            a1 = *(const float4*)(Arow + k0 + 4);
        }
        float4 w0 = *(const float4*)(Wrow + k0);
        float4 w1 = *(const float4*)(Wrow + k0 + 4);
        As[lkc+0][lrow] = a0.x; As[lkc+1][lrow] = a0.y;
        As[lkc+2][lrow] = a0.z; As[lkc+3][lrow] = a0.w;
        As[lkc+4][lrow] = a1.x; As[lkc+5][lrow] = a1.y;
        As[lkc+6][lrow] = a1.z; As[lkc+7][lrow] = a1.w;
        Ws[lkc+0][lrow] = w0.x; Ws[lkc+1][lrow] = w0.y;
        Ws[lkc+2][lrow] = w0.z; Ws[lkc+3][lrow] = w0.w;
        Ws[lkc+4][lrow] = w1.x; Ws[lkc+5][lrow] = w1.y;
        Ws[lkc+6][lrow] = w1.z; Ws[lkc+7][lrow] = w1.w;
        __syncthreads();
        #pragma unroll
        for (int kk = 0; kk < 32; ++kk) {
            float4 a = *(const float4*)(&As[kk][ty*4]);
            float4 ww = *(const float4*)(&Ws[kk][tx*4]);
            acc[0][0] += a.x*ww.x; acc[0][1] += a.x*ww.y; acc[0][2] += a.x*ww.z; acc[0][3] += a.x*ww.w;
            acc[1][0] += a.y*ww.x; acc[1][1] += a.y*ww.y; acc[1][2] += a.y*ww.z; acc[1][3] += a.y*ww.w;
            acc[2][0] += a.z*ww.x; acc[2][1] += a.z*ww.y; acc[2][2] += a.z*ww.z; acc[2][3] += a.z*ww.w;
            acc[3][0] += a.w*ww.x; acc[3][1] += a.w*ww.y; acc[3][2] += a.w*ww.z; acc[3][3] += a.w*ww.w;
        }
        __syncthreads();
    }
    #pragma unroll
    for (int i = 0; i < 4; ++i) {
        int m = m0 + ty*4 + i;
        if (m >= M) continue;
        #pragma unroll
        for (int j = 0; j < 4; ++j) {
            int e = e0 + tx*4 + j;
            C[(size_t)m * E + e] = acc[i][j] + bias[e];
        }
    }
}

// ---------------- V transpose: [s][b][h*64+d] bf16 -> [bh][d][1024] bf16 ----------------
__global__ __launch_bounds__(256)
void vtr_kernel(const unsigned short* __restrict__ vin,
                unsigned short* __restrict__ vout) {
    __shared__ unsigned short T[64][65];
    int tt = blockIdx.x;
    int bh = blockIdx.y;
    int b = bh >> 4, h = bh & 15;
    int tid = threadIdx.x;
    #pragma unroll
    for (int rep = 0; rep < 2; ++rep) {
        int slot = rep * 256 + tid;
        int r = slot >> 3, ch = slot & 7;
        int t = tt * 64 + r;
        unsigned short e[8] = {0,0,0,0,0,0,0,0};
        if (t < S_) {
            const unsigned short* src = vin + ((size_t)t * B_ + b) * D_ + h * HD_ + ch * 8;
            *(ushort4*)&e[0] = *(const ushort4*)(src);
            *(ushort4*)&e[4] = *(const ushort4*)(src + 4);
        }
        #pragma unroll
        for (int u = 0; u < 8; ++u) T[r][ch*8+u] = e[u];
    }
    __syncthreads();
    #pragma unroll
    for (int rep = 0; rep < 2; ++rep) {
        int slot = rep * 256 + tid;
        int d = slot >> 3, ch = slot & 7;
        unsigned short e[8];
        #pragma unroll
        for (int u = 0; u < 8; ++u) e[u] = T[ch*8+u][d];
        unsigned short* dst = vout + ((size_t)bh * 64 + d) * 1024 + tt * 64 + ch * 8;
        *(ushort4*)(dst)     = *(ushort4*)&e[0];
        *(ushort4*)(dst + 4) = *(ushort4*)&e[4];
    }
}

// ---------------- bf16 MFMA flash attention: 64 q x (b,h), KVBLK=128 ----------------
// 256 thr / 4 waves x 16 q-rows. One stage + one barrier pair + ONE O-rescale
// per 128 kv (vs 64) -> halves barrier count and rescale VALU.
// LDS 48 KB: Ks[128][64] 16K + Vs[64][128] 16K + Ps[4][16][128] 16K -> 3 blk/CU.
__global__ __launch_bounds__(256)
void mattn_kernel(const unsigned short* __restrict__ qg,
                  const unsigned short* __restrict__ kg,
                  const unsigned short* __restrict__ vt,
                  unsigned short* __restrict__ o) {
    __shared__ __align__(16) unsigned short Ks[128 * 64];
    __shared__ __align__(16) unsigned short Vs[64 * 128];
    __shared__ __align__(16) unsigned short Ps[4][16 * 128];

    int bid = blockIdx.x;
    int qt = bid & 15;
    int bh = bid >> 4;
    int b = bh >> 4, h = bh & 15;
    int tid = threadIdx.x;
    int w = tid >> 6, lane = tid & 63;
    int l15 = lane & 15, l4 = lane >> 4, l7 = lane & 7;
    int q0 = qt * 64 + w * 16;

    bf16x8 qfr[2];
    {
        int qr = q0 + l15; if (qr > S_ - 1) qr = S_ - 1;
        const unsigned short* qrow = qg + ((size_t)qr * B_ + b) * D_ + h * HD_;
        qfr[0] = *(const bf16x8*)(qrow + l4 * 8);
        qfr[1] = *(const bf16x8*)(qrow + 32 + l4 * 8);
    }

    f32x4 accO[4] = {};
    float mreg[4] = {-1e30f, -1e30f, -1e30f, -1e30f};
    float lreg[4] = {0.f, 0.f, 0.f, 0.f};

    for (int t0 = 0; t0 < 1024; t0 += 128) {
        __syncthreads();
        // stage K: 128 rows x 8 chunks (1024 slots, 4/thread)
        #pragma unroll
        for (int rep = 0; rep < 4; ++rep) {
            int slot = rep * 256 + tid;
            int r = slot >> 3, c = slot & 7;
            int tr = t0 + r; if (tr > S_ - 1) tr = S_ - 1;
            gl16(kg + ((size_t)tr * B_ + b) * D_ + h * HD_ + (c ^ (r & 7)) * 8,
                 &Ks[slot * 8]);
        }
        // stage V: 64 d-rows x 16 chunks (1024 slots, 4/thread)
        #pragma unroll
        for (int rep = 0; rep < 4; ++rep) {
            int slot = rep * 256 + tid;
            int r = slot >> 4, c = slot & 15;
            gl16(vt + ((size_t)bh * 64 + r) * 1024 + t0 + (c ^ (r & 7)) * 8,
                 &Vs[slot * 8]);
        }
        __syncthreads();

        // ---- QK^T: s[j] covers t-cols j*16+l15, j=0..7 ----
        f32x4 s[8] = {};
        #pragma unroll
        for (int ks = 0; ks < 2; ++ks) {
            unsigned soff = (unsigned)((((ks * 4) + l4) ^ l7) * 16);
            #pragma unroll
            for (int j = 0; j < 8; ++j) {
                bf16x8 kf = *(const bf16x8*)((const char*)Ks + (j*16 + l15) * 128 + soff);
                s[j] = __builtin_amdgcn_mfma_f32_16x16x32_bf16(qfr[ks], kf, s[j], 0, 0, 0);
            }
        }
        #pragma unroll
        for (int j = 0; j < 8; ++j) {
            int t = t0 + j * 16 + l15;
            if (t >= S_) { s[j][0] = -1e30f; s[j][1] = -1e30f; s[j][2] = -1e30f; s[j][3] = -1e30f; }
        }
        // ---- online softmax: ONE rescale per 128 kv ----
        float rm[4], sc[4], rsum[4];
        #pragma unroll
        for (int r = 0; r < 4; ++r) {
            rm[r] = fmaxf(fmaxf(s[0][r], s[1][r]), fmaxf(s[2][r], s[3][r]));
            rm[r] = fmaxf(rm[r], fmaxf(fmaxf(s[4][r], s[5][r]), fmaxf(s[6][r], s[7][r])));
        }
        #pragma unroll
        for (int mk = 1; mk <= 8; mk <<= 1) {
            #pragma unroll
            for (int r = 0; r < 4; ++r) rm[r] = fmaxf(rm[r], __shfl_xor(rm[r], mk));
        }
        #pragma unroll
        for (int r = 0; r < 4; ++r) {
            float mn = fmaxf(mreg[r], rm[r]);
            sc[r] = __expf(mreg[r] - mn);
            mreg[r] = mn;
            rsum[r] = 0.f;
        }
        #pragma unroll
        for (int j = 0; j < 8; ++j) {
            int inb = (j * 16 + l15) * 2;            // byte col in 256B row
            #pragma unroll
            for (int r = 0; r < 4; ++r) {
                float p = __expf(s[j][r] - mreg[r]);
                rsum[r] += p;
                int row = l4 * 4 + r;
                *(unsigned short*)((char*)&Ps[w][0] + row * 256 +
                    ((((inb >> 4) ^ (row & 7)) << 4)) + (inb & 15)) = f2b(p);
            }
        }
        #pragma unroll
        for (int mk = 1; mk <= 8; mk <<= 1) {
            #pragma unroll
            for (int r = 0; r < 4; ++r) rsum[r] += __shfl_xor(rsum[r], mk);
        }
        #pragma unroll
        for (int r = 0; r < 4; ++r) lreg[r] = lreg[r] * sc[r] + rsum[r];
        #pragma unroll
        for (int j = 0; j < 4; ++j) {
            accO[j][0] *= sc[0]; accO[j][1] *= sc[1];
            accO[j][2] *= sc[2]; accO[j][3] *= sc[3];
        }
        // ---- PV: A = Ps (16q x 128t), B = Vs (64d x 128t); 4 k-slices ----
        #pragma unroll
        for (int ks = 0; ks < 4; ++ks) {
            unsigned soff = (unsigned)((((ks * 4) + l4) ^ l7) * 16);
            bf16x8 pf = *(const bf16x8*)((const char*)&Ps[w][0] + l15 * 256 + soff);
            #pragma unroll
            for (int j = 0; j < 4; ++j) {
                bf16x8 vf = *(const bf16x8*)((const char*)Vs + (j*16 + l15) * 256 + soff);
                accO[j] = __builtin_amdgcn_mfma_f32_16x16x32_bf16(pf, vf, accO[j], 0, 0, 0);
            }
        }
    }
    #pragma unroll
    for (int r = 0; r < 4; ++r) {
        int q = q0 + l4 * 4 + r;
        if (q >= S_) continue;
        float inv = 1.0f / lreg[r];
        unsigned short* orow = o + ((size_t)q * B_ + b) * D_ + h * HD_;
        #pragma unroll
        for (int j = 0; j < 4; ++j)
            orow[j * 16 + l15] = f2b(accO[j][r] * inv);
    }
}

extern "C" void kernel_launch(void* const* d_in, const int* in_sizes, int n_in,
                              void* d_out, int out_size, void* d_ws, size_t ws_size,
                              hipStream_t stream) {
    const int*   tokens = (const int*)  d_in[0];
    const float* Wemb   = (const float*)d_in[1];
    const float* Wq     = (const float*)d_in[2];
    const float* bq     = (const float*)d_in[3];
    const float* Wk     = (const float*)d_in[4];
    const float* bk     = (const float*)d_in[5];
    const float* Wv     = (const float*)d_in[6];
    const float* bv     = (const float*)d_in[7];
    const float* Wo     = (const float*)d_in[8];
    const float* bo     = (const float*)d_in[9];
    const float* ln1g   = (const float*)d_in[10];
    const float* ln1b   = (const float*)d_in[11];
    const float* ln2g   = (const float*)d_in[12];
    const float* ln2b   = (const float*)d_in[13];
    const float* W1     = (const float*)d_in[14];
    const float* b1     = (const float*)d_in[15];
    const float* W2     = (const float*)d_in[16];
    const float* b2     = (const float*)d_in[17];
    const float* Wout   = (const float*)d_in[18];
    const float* bout   = (const float*)d_in[19];
    float* out = (float*)d_out;

    const size_t ND = (size_t)N_ * D_;
    const size_t NF = (size_t)N_ * FF_;
    const size_t M1 = (size_t)D_ * D_;
    const size_t M4 = (size_t)FF_ * D_;
    const size_t VT = (size_t)64 * 64 * 1024;

    float* x  = (float*)d_ws;
    unsigned short* hb = (unsigned short*)(x + ND);
    unsigned short* qb = hb + ND;
    unsigned short* kb = qb + ND;
    unsigned short* vb = kb + ND;
    unsigned short* ob = vb + ND;
    unsigned short* vt = ob + ND;
    unsigned short* f1 = vt + VT;
    unsigned short* wb = f1 + NF;           // 12M bf16 per-layer weights

    dim3 blk(256);
    embed_kernel<<<N_, blk, 0, stream>>>(tokens, Wemb, x);

    dim3 gQKV(16, 48);   // 256x64 tiles: M=4000->16, E=3072->48 (768 blocks)
    dim3 gW1(32, 64);    // 128x64 tiles: E=4096->64 (2048 blocks)
    dim3 gE64(32, 16);   // 128x64 tiles, E=1024->16 (512 blocks)
    dim3 gCv(12288);
    dim3 gVt(16, 64);
    dim3 gAt(16 * 64);   // 16 q-tiles of 64 x 64 (b,h)
    dim3 gOut((N_ + 63) / 64, 1);

    for (int l = 0; l < L_; ++l) {
        cvtw_kernel<<<gCv, blk, 0, stream>>>(Wq + l*M1, Wk + l*M1, Wv + l*M1,
                                             Wo + l*M1, W1 + l*M4, W2 + l*M4, wb);
        ln_kernel<<<N_, blk, 0, stream>>>(x, ln1g + l*D_, ln1b + l*D_, hb);
        ggemm_kernel<<<gQKV, dim3(512), 0, stream>>>(hb, wb,
            bq + l*D_, bk + l*D_, bv + l*D_, qb, kb, vb, N_, D_);
        vtr_kernel<<<gVt, blk, 0, stream>>>(vb, vt);
        mattn_kernel<<<gAt, blk, 0, stream>>>(qb, kb, vt, ob);
        dgemm_kernel<0><<<gE64, blk, 0, stream>>>(ob, wb + 3*M1,
            bo + l*D_, x, x, N_, D_);
        ln_kernel<<<N_, blk, 0, stream>>>(x, ln2g + l*D_, ln2b + l*D_, hb);
        dgemm_kernel<1><<<gW1, blk, 0, stream>>>(hb, wb + 4*M1,
            b1 + l*FF_, nullptr, f1, N_, D_);
        dgemm_kernel<0><<<gE64, blk, 0, stream>>>(f1, wb + 4*M1 + M4,
            b2 + l*D_, x, x, N_, FF_);
    }
    gemm_kernel<<<gOut, blk, 0, stream>>>(x, Wout, bout, out, N_, D_, 64);
}

// Round 19
// 1086.084 us; speedup vs baseline: 1.0347x; 1.0296x over previous
//
#include <hip/hip_runtime.h>
#include <hip/hip_bf16.h>
#include <math.h>

#define S_   1000
#define B_   4
#define D_   1024
#define H_   16
#define HD_  64
#define L_   4
#define FF_  4096
#define N_   (S_*B_)   /* 4000 token rows */

typedef __bf16 bf16x8 __attribute__((ext_vector_type(8)));
typedef float  f32x4  __attribute__((ext_vector_type(4)));
typedef __attribute__((address_space(3))) unsigned short lds_u16;

__device__ __forceinline__ unsigned short f2b(float f) {
    unsigned u = __builtin_bit_cast(unsigned, f);
    u = (u + 0x7FFFu + ((u >> 16) & 1u)) >> 16;   // RNE
    return (unsigned short)u;
}
__device__ __forceinline__ float b2f(unsigned short s) {
    unsigned u = (unsigned)s << 16;
    return __builtin_bit_cast(float, u);
}

__device__ __forceinline__ void gl16(const void* g, void* l) {
    __builtin_amdgcn_global_load_lds(
        (const __attribute__((address_space(1))) unsigned int*)g,
        (__attribute__((address_space(3))) unsigned int*)l, 16, 0, 0);
}

// inline-asm LDS read: invisible to compiler's mem-dep model, so it cannot
// auto-insert vmcnt(0) between global_load_lds and this read.
__device__ __forceinline__ bf16x8 ldsr(unsigned addr) {
    bf16x8 r;
    asm volatile("ds_read_b128 %0, %1" : "=v"(r) : "v"(addr));
    return r;
}

// ---------------- embedding lookup ----------------
__global__ void embed_kernel(const int* __restrict__ tokens,
                             const float* __restrict__ emb,
                             float* __restrict__ x) {
    int n = blockIdx.x;
    int tok = tokens[n];
    const float4* src = (const float4*)(emb + (size_t)tok * D_);
    float4* dst = (float4*)(x + (size_t)n * D_);
    dst[threadIdx.x] = src[threadIdx.x];
}

// ---------------- weight fp32->bf16 conversion (one layer, 12M elems) ----------------
__global__ __launch_bounds__(256)
void cvtw_kernel(const float* __restrict__ wq, const float* __restrict__ wk,
                 const float* __restrict__ wv, const float* __restrict__ wo,
                 const float* __restrict__ w1, const float* __restrict__ w2,
                 unsigned short* __restrict__ dst) {
    const size_t M1 = (size_t)D_ * D_;
    const size_t M4 = (size_t)FF_ * D_;
    size_t i = ((size_t)blockIdx.x * 256 + threadIdx.x) * 4;
    const float* src; size_t off;
    if      (i < M1)        { src = wq; off = i; }
    else if (i < 2*M1)      { src = wk; off = i - M1; }
    else if (i < 3*M1)      { src = wv; off = i - 2*M1; }
    else if (i < 4*M1)      { src = wo; off = i - 3*M1; }
    else if (i < 4*M1+M4)   { src = w1; off = i - 4*M1; }
    else                    { src = w2; off = i - 4*M1 - M4; }
    float4 v = *(const float4*)(src + off);
    ushort4 u;
    u.x = f2b(v.x); u.y = f2b(v.y); u.z = f2b(v.z); u.w = f2b(v.w);
    *(ushort4*)(dst + i) = u;
}

// ---------------- layernorm: fp32 in, bf16 out ----------------
__global__ __launch_bounds__(256)
void ln_kernel(const float* __restrict__ in,
               const float* __restrict__ g,
               const float* __restrict__ b,
               unsigned short* __restrict__ out) {
    int n = blockIdx.x;
    int tid = threadIdx.x;
    const float4* row = (const float4*)(in + (size_t)n * D_);
    float4 v = row[tid];
    float s  = v.x + v.y + v.z + v.w;
    float sq = v.x*v.x + v.y*v.y + v.z*v.z + v.w*v.w;
    #pragma unroll
    for (int off = 32; off; off >>= 1) {
        s  += __shfl_down(s, off);
        sq += __shfl_down(sq, off);
    }
    __shared__ float rs[4], rq[4];
    int wid = tid >> 6;
    if ((tid & 63) == 0) { rs[wid] = s; rq[wid] = sq; }
    __syncthreads();
    s  = rs[0] + rs[1] + rs[2] + rs[3];
    sq = rq[0] + rq[1] + rq[2] + rq[3];
    float mean = s * (1.0f / D_);
    float var  = sq * (1.0f / D_) - mean * mean;
    float rstd = rsqrtf(var + 1e-5f);
    float4 gg = ((const float4*)g)[tid];
    float4 bb = ((const float4*)b)[tid];
    ushort4 o;
    o.x = f2b((v.x - mean) * rstd * gg.x + bb.x);
    o.y = f2b((v.y - mean) * rstd * gg.y + bb.y);
    o.z = f2b((v.z - mean) * rstd * gg.z + bb.z);
    o.w = f2b((v.w - mean) * rstd * gg.w + bb.w);
    ((ushort4*)(out + (size_t)n * D_))[tid] = o;
}

// ---------------- 256x64 asm-ds_read 2-phase GEMM, 512 thr, wave tile 32x64 ----------------
// (round-14 proven) QKV split + fused RoPE — o0/o1/o2 bf16 stride 1024, q *0.125
__global__ __launch_bounds__(512, 4)
void ggemm_kernel(const unsigned short* __restrict__ A,
                  const unsigned short* __restrict__ W,
                  const float* __restrict__ bb0, const float* __restrict__ bb1,
                  const float* __restrict__ bb2,
                  unsigned short* __restrict__ o0, unsigned short* __restrict__ o1,
                  unsigned short* __restrict__ o2,
                  int M, int K) {
    __shared__ __align__(16) unsigned short As[2][256 * 64];   // 64 KB
    __shared__ __align__(16) unsigned short Bs[2][64 * 64];    // 16 KB
    int tid = threadIdx.x;
    int w = tid >> 6, lane = tid & 63;
    int m0 = blockIdx.x * 256, e0 = blockIdx.y * 64;
    int l15 = lane & 15, l4 = lane >> 4, l7 = lane & 7;

    f32x4 acc[2][4] = {};

    auto stage = [&](int buf, int kt) {
        #pragma unroll
        for (int rep = 0; rep < 4; ++rep) {
            int slot = rep * 512 + tid;            // A: 256 rows x 8 chunks
            int r = slot >> 3, c = slot & 7;
            int ar = m0 + r; if (ar > M - 1) ar = M - 1;
            gl16(A + (size_t)ar * K + kt + (c ^ (r & 7)) * 8, &As[buf][slot * 8]);
        }
        {
            int slot = tid;                        // B: 64 rows x 8 chunks
            int r = slot >> 3, c = slot & 7;
            gl16(W + (size_t)(e0 + r) * K + kt + (c ^ (r & 7)) * 8, &Bs[buf][slot * 8]);
        }
    };

    int aoff[2], boff[4];
    #pragma unroll
    for (int i = 0; i < 2; ++i) aoff[i] = (w * 32 + i * 16 + l15) * 128;
    #pragma unroll
    for (int j = 0; j < 4; ++j) boff[j] = (j * 16 + l15) * 128;

    stage(0, 0);
    asm volatile("s_waitcnt vmcnt(0)" ::: "memory");
    __builtin_amdgcn_sched_barrier(0);
    __builtin_amdgcn_s_barrier();

    int nk = K >> 6;
    for (int t = 0; t < nk; ++t) {
        int cur = t & 1;
        if (t + 1 < nk) stage(cur ^ 1, (t + 1) << 6);
        __builtin_amdgcn_sched_barrier(0);
        unsigned aB = (unsigned)(size_t)(lds_u16*)&As[cur][0];
        unsigned bB = (unsigned)(size_t)(lds_u16*)&Bs[cur][0];
        #pragma unroll
        for (int ks = 0; ks < 2; ++ks) {
            unsigned soff = (unsigned)((((ks * 4) + l4) ^ l7) * 16);
            bf16x8 av[2], bv[4];
            #pragma unroll
            for (int i = 0; i < 2; ++i) av[i] = ldsr(aB + aoff[i] + soff);
            #pragma unroll
            for (int j = 0; j < 4; ++j) bv[j] = ldsr(bB + boff[j] + soff);
            asm volatile("s_waitcnt lgkmcnt(0)" ::: "memory");
            __builtin_amdgcn_sched_barrier(0);
            __builtin_amdgcn_s_setprio(1);
            #pragma unroll
            for (int i = 0; i < 2; ++i)
                #pragma unroll
                for (int j = 0; j < 4; ++j)
                    acc[i][j] = __builtin_amdgcn_mfma_f32_16x16x32_bf16(av[i], bv[j], acc[i][j], 0, 0, 0);
            __builtin_amdgcn_s_setprio(0);
        }
        asm volatile("s_waitcnt vmcnt(0)" ::: "memory");
        __builtin_amdgcn_sched_barrier(0);
        __builtin_amdgcn_s_barrier();
    }

    // ---- epilogue (C/D: col=lane&15, row=(lane>>4)*4+reg) ----
    int sel = e0 >> 10;                     // 64-tile never crosses 1024 boundary
    int eobase = e0 & 1023;
    const float* bp = (sel == 0) ? bb0 : (sel == 1) ? bb1 : bb2;
    unsigned short* op = (sel == 0) ? o0 : (sel == 1) ? o1 : o2;
    if (sel == 2) {
        #pragma unroll
        for (int i = 0; i < 2; ++i) {
            int mrow = m0 + w*32 + i*16 + l4*4;
            #pragma unroll
            for (int j = 0; j < 4; ++j) {
                int eo = eobase + j*16 + l15;
                float bval = bp[eo];
                #pragma unroll
                for (int r = 0; r < 4; ++r) {
                    int m = mrow + r;
                    if (m >= M) continue;
                    op[(size_t)m * 1024 + eo] = f2b(acc[i][j][r] + bval);
                }
            }
        }
    } else {
        // fused RoPE: pair (d, d+32) = acc[i][jj], acc[i][jj+2]; rotate on fp32
        float scale = (sel == 0) ? 0.125f : 1.0f;
        #pragma unroll
        for (int i = 0; i < 2; ++i) {
            int mrow = m0 + w*32 + i*16 + l4*4;
            #pragma unroll
            for (int jj = 0; jj < 2; ++jj) {
                int d5 = jj*16 + l15;                 // 0..31 within head
                int eo_a = eobase + d5;
                int eo_b = eo_a + 32;
                float ba = bp[eo_a], bbv = bp[eo_b];
                float invf = __expf(-(float)d5 * 0.2878231366242557f); // ln(1e4)/32
                #pragma unroll
                for (int r = 0; r < 4; ++r) {
                    int m = mrow + r;
                    if (m >= M) continue;
                    int s = m >> 2;                   // n = s*B + b, B=4
                    float ang = (float)s * invf;
                    float sn, cs;
                    __sincosf(ang, &sn, &cs);
                    float a = acc[i][jj][r]   + ba;
                    float c = acc[i][jj+2][r] + bbv;
                    op[(size_t)m * 1024 + eo_a] = f2b((a*cs - c*sn) * scale);
                    op[(size_t)m * 1024 + eo_b] = f2b((c*cs + a*sn) * scale);
                }
            }
        }
    }
}

// ---------------- 128x64 asm-ds_read 2-phase GEMM (best per-FLOP structure) ----------------
// 4 waves 2x2, wave tile 64x32, 48 KB LDS -> 3 blocks/CU.
// MODE 0: +residual — out fp32 stride 1024
// MODE 1: GELU — out bf16 stride FF_
template<int MODE>
__global__ __launch_bounds__(256, 2)
void dgemm_kernel(const unsigned short* __restrict__ A,
                  const unsigned short* __restrict__ W,
                  const float* __restrict__ bias,
                  const float* __restrict__ res,
                  void* __restrict__ outv,
                  int M, int K) {
    __shared__ __align__(16) unsigned short As[2][128 * 64];   // 32 KB
    __shared__ __align__(16) unsigned short Bs[2][64 * 64];    // 16 KB
    int tid = threadIdx.x;
    int w = tid >> 6, lane = tid & 63;
    int wr = w >> 1, wc = w & 1;
    int m0 = blockIdx.x * 128, e0 = blockIdx.y * 64;
    int l15 = lane & 15, l4 = lane >> 4, l7 = lane & 7;

    f32x4 acc[4][2] = {};

    auto stage = [&](int buf, int kt) {
        #pragma unroll
        for (int rep = 0; rep < 4; ++rep) {
            int slot = rep * 256 + tid;            // A: 128 rows
            int r = slot >> 3, c = slot & 7;
            int ar = m0 + r; if (ar > M - 1) ar = M - 1;
            gl16(A + (size_t)ar * K + kt + (c ^ (r & 7)) * 8, &As[buf][slot * 8]);
        }
        #pragma unroll
        for (int rep = 0; rep < 2; ++rep) {
            int slot = rep * 256 + tid;            // B: 64 rows
            int r = slot >> 3, c = slot & 7;
            gl16(W + (size_t)(e0 + r) * K + kt + (c ^ (r & 7)) * 8, &Bs[buf][slot * 8]);
        }
    };

    int aoff[4], boff[2];
    #pragma unroll
    for (int i = 0; i < 4; ++i) aoff[i] = (wr * 64 + i * 16 + l15) * 128;
    #pragma unroll
    for (int j = 0; j < 2; ++j) boff[j] = (wc * 32 + j * 16 + l15) * 128;

    stage(0, 0);
    asm volatile("s_waitcnt vmcnt(0)" ::: "memory");
    __builtin_amdgcn_sched_barrier(0);
    __builtin_amdgcn_s_barrier();

    int nk = K >> 6;
    for (int t = 0; t < nk; ++t) {
        int cur = t & 1;
        if (t + 1 < nk) stage(cur ^ 1, (t + 1) << 6);
        __builtin_amdgcn_sched_barrier(0);
        unsigned aB = (unsigned)(size_t)(lds_u16*)&As[cur][0];
        unsigned bB = (unsigned)(size_t)(lds_u16*)&Bs[cur][0];
        #pragma unroll
        for (int ks = 0; ks < 2; ++ks) {
            unsigned soff = (unsigned)((((ks * 4) + l4) ^ l7) * 16);
            bf16x8 av[4], bv[2];
            #pragma unroll
            for (int i = 0; i < 4; ++i) av[i] = ldsr(aB + aoff[i] + soff);
            #pragma unroll
            for (int j = 0; j < 2; ++j) bv[j] = ldsr(bB + boff[j] + soff);
            asm volatile("s_waitcnt lgkmcnt(0)" ::: "memory");
            __builtin_amdgcn_sched_barrier(0);
            __builtin_amdgcn_s_setprio(1);
            #pragma unroll
            for (int i = 0; i < 4; ++i)
                #pragma unroll
                for (int j = 0; j < 2; ++j)
                    acc[i][j] = __builtin_amdgcn_mfma_f32_16x16x32_bf16(av[i], bv[j], acc[i][j], 0, 0, 0);
            __builtin_amdgcn_s_setprio(0);
        }
        asm volatile("s_waitcnt vmcnt(0)" ::: "memory");
        __builtin_amdgcn_sched_barrier(0);
        __builtin_amdgcn_s_barrier();
    }

    if (MODE == 0) {
        float* out = (float*)outv;
        #pragma unroll
        for (int i = 0; i < 4; ++i) {
            int mrow = m0 + wr*64 + i*16 + l4*4;
            #pragma unroll
            for (int j = 0; j < 2; ++j) {
                int e = e0 + wc*32 + j*16 + l15;
                float bval = bias[e];
                #pragma unroll
                for (int r = 0; r < 4; ++r) {
                    int m = mrow + r;
                    if (m >= M) continue;
                    out[(size_t)m * 1024 + e] = acc[i][j][r] + bval + res[(size_t)m * 1024 + e];
                }
            }
        }
    } else {
        unsigned short* out = (unsigned short*)outv;
        #pragma unroll
        for (int i = 0; i < 4; ++i) {
            int mrow = m0 + wr*64 + i*16 + l4*4;
            #pragma unroll
            for (int j = 0; j < 2; ++j) {
                int e = e0 + wc*32 + j*16 + l15;
                float bval = bias[e];
                #pragma unroll
                for (int r = 0; r < 4; ++r) {
                    int m = mrow + r;
                    if (m >= M) continue;
                    float val = acc[i][j][r] + bval;
                    val = 0.5f * val * (1.0f + erff(val * 0.70710678118654752f));
                    out[(size_t)m * FF_ + e] = f2b(val);
                }
            }
        }
    }
}

// ---------------- fp32 tiled GEMM (final 64-col projection only) ----------------
__global__ __launch_bounds__(256)
void gemm_kernel(const float* __restrict__ A, const float* __restrict__ W,
                 const float* __restrict__ bias, float* __restrict__ C,
                 int M, int K, int E) {
    __shared__ float As[32][64];
    __shared__ float Ws[32][64];
    int tid = threadIdx.x;
    int m0 = blockIdx.x * 64, e0 = blockIdx.y * 64;
    int tx = tid & 15, ty = tid >> 4;
    int lrow = tid >> 2;
    int lkc  = (tid & 3) * 8;
    float acc[4][4] = {};
    const float* Arow = A + (size_t)(m0 + lrow) * K + lkc;
    const float* Wrow = W + (size_t)(e0 + lrow) * K + lkc;
    bool aval = (m0 + lrow) < M;

    for (int k0 = 0; k0 < K; k0 += 32) {
        float4 a0 = make_float4(0.f,0.f,0.f,0.f), a1 = a0;
        if (aval) {
            a0 = *(const float4*)(Arow + k0);
            a1 = *(const float4*)(Arow + k0 + 4);
        }
        float4 w0 = *(const float4*)(Wrow + k0);
        float4 w1 = *(const float4*)(Wrow + k0 + 4);
        As[lkc+0][lrow] = a0.x; As[lkc+1][lrow] = a0.y;
        As[lkc+2][lrow] = a0.z; As[lkc+3][lrow] = a0.w;
        As[lkc+4][lrow] = a1.x; As[lkc+5][lrow] = a1.y;
        As[lkc+6][lrow] = a1.z; As[lkc+7][lrow] = a1.w;
        Ws[lkc+0][lrow] = w0.x; Ws[lkc+1][lrow] = w0.y;
        Ws[lkc+2][lrow] = w0.z; Ws[lkc+3][lrow] = w0.w;
        Ws[lkc+4][lrow] = w1.x; Ws[lkc+5][lrow] = w1.y;
        Ws[lkc+6][lrow] = w1.z; Ws[lkc+7][lrow] = w1.w;
        __syncthreads();
        #pragma unroll
        for (int kk = 0; kk < 32; ++kk) {
            float4 a = *(const float4*)(&As[kk][ty*4]);
            float4 ww = *(const float4*)(&Ws[kk][tx*4]);
            acc[0][0] += a.x*ww.x; acc[0][1] += a.x*ww.y; acc[0][2] += a.x*ww.z; acc[0][3] += a.x*ww.w;
            acc[1][0] += a.y*ww.x; acc[1][1] += a.y*ww.y; acc[1][2] += a.y*ww.z; acc[1][3] += a.y*ww.w;
            acc[2][0] += a.z*ww.x; acc[2][1] += a.z*ww.y; acc[2][2] += a.z*ww.z; acc[2][3] += a.z*ww.w;
            acc[3][0] += a.w*ww.x; acc[3][1] += a.w*ww.y; acc[3][2] += a.w*ww.z; acc[3][3] += a.w*ww.w;
        }
        __syncthreads();
    }
    #pragma unroll
    for (int i = 0; i < 4; ++i) {
        int m = m0 + ty*4 + i;
        if (m >= M) continue;
        #pragma unroll
        for (int j = 0; j < 4; ++j) {
            int e = e0 + tx*4 + j;
            C[(size_t)m * E + e] = acc[i][j] + bias[e];
        }
    }
}

// ---------------- V transpose: [s][b][h*64+d] bf16 -> [bh][d][1024] bf16 ----------------
__global__ __launch_bounds__(256)
void vtr_kernel(const unsigned short* __restrict__ vin,
                unsigned short* __restrict__ vout) {
    __shared__ unsigned short T[64][65];
    int tt = blockIdx.x;
    int bh = blockIdx.y;
    int b = bh >> 4, h = bh & 15;
    int tid = threadIdx.x;
    #pragma unroll
    for (int rep = 0; rep < 2; ++rep) {
        int slot = rep * 256 + tid;
        int r = slot >> 3, ch = slot & 7;
        int t = tt * 64 + r;
        unsigned short e[8] = {0,0,0,0,0,0,0,0};
        if (t < S_) {
            const unsigned short* src = vin + ((size_t)t * B_ + b) * D_ + h * HD_ + ch * 8;
            *(ushort4*)&e[0] = *(const ushort4*)(src);
            *(ushort4*)&e[4] = *(const ushort4*)(src + 4);
        }
        #pragma unroll
        for (int u = 0; u < 8; ++u) T[r][ch*8+u] = e[u];
    }
    __syncthreads();
    #pragma unroll
    for (int rep = 0; rep < 2; ++rep) {
        int slot = rep * 256 + tid;
        int d = slot >> 3, ch = slot & 7;
        unsigned short e[8];
        #pragma unroll
        for (int u = 0; u < 8; ++u) e[u] = T[ch*8+u][d];
        unsigned short* dst = vout + ((size_t)bh * 64 + d) * 1024 + tt * 64 + ch * 8;
        *(ushort4*)(dst)     = *(ushort4*)&e[0];
        *(ushort4*)(dst + 4) = *(ushort4*)&e[4];
    }
}

// ---------------- bf16 MFMA flash attention: 64 q x (b,h), KVBLK=128 ----------------
// 256 thr / 4 waves x 16 q-rows. Softmax denominators computed on the MATRIX
// pipe: accS = mfma(P, ones) accumulates row sums with the same online
// rescale recurrence as lreg (deletes the rsum shuffle-reduce chain).
// LDS 48 KB: Ks[128][64] 16K + Vs[64][128] 16K + Ps[4][16][128] 16K -> 3 blk/CU.
__global__ __launch_bounds__(256)
void mattn_kernel(const unsigned short* __restrict__ qg,
                  const unsigned short* __restrict__ kg,
                  const unsigned short* __restrict__ vt,
                  unsigned short* __restrict__ o) {
    __shared__ __align__(16) unsigned short Ks[128 * 64];
    __shared__ __align__(16) unsigned short Vs[64 * 128];
    __shared__ __align__(16) unsigned short Ps[4][16 * 128];

    int bid = blockIdx.x;
    int qt = bid & 15;
    int bh = bid >> 4;
    int b = bh >> 4, h = bh & 15;
    int tid = threadIdx.x;
    int w = tid >> 6, lane = tid & 63;
    int l15 = lane & 15, l4 = lane >> 4, l7 = lane & 7;
    int q0 = qt * 64 + w * 16;

    bf16x8 qfr[2];
    {
        int qr = q0 + l15; if (qr > S_ - 1) qr = S_ - 1;
        const unsigned short* qrow = qg + ((size_t)qr * B_ + b) * D_ + h * HD_;
        qfr[0] = *(const bf16x8*)(qrow + l4 * 8);
        qfr[1] = *(const bf16x8*)(qrow + 32 + l4 * 8);
    }
    bf16x8 onesf;
    #pragma unroll
    for (int z = 0; z < 8; ++z) onesf[z] = (__bf16)1.0f;

    f32x4 accO[4] = {};
    f32x4 accS = {0.f, 0.f, 0.f, 0.f};          // MFMA-computed row sums
    float mreg[4] = {-1e30f, -1e30f, -1e30f, -1e30f};

    for (int t0 = 0; t0 < 1024; t0 += 128) {
        __syncthreads();
        // stage K: 128 rows x 8 chunks (1024 slots, 4/thread)
        #pragma unroll
        for (int rep = 0; rep < 4; ++rep) {
            int slot = rep * 256 + tid;
            int r = slot >> 3, c = slot & 7;
            int tr = t0 + r; if (tr > S_ - 1) tr = S_ - 1;
            gl16(kg + ((size_t)tr * B_ + b) * D_ + h * HD_ + (c ^ (r & 7)) * 8,
                 &Ks[slot * 8]);
        }
        // stage V: 64 d-rows x 16 chunks (1024 slots, 4/thread)
        #pragma unroll
        for (int rep = 0; rep < 4; ++rep) {
            int slot = rep * 256 + tid;
            int r = slot >> 4, c = slot & 15;
            gl16(vt + ((size_t)bh * 64 + r) * 1024 + t0 + (c ^ (r & 7)) * 8,
                 &Vs[slot * 8]);
        }
        __syncthreads();

        // ---- QK^T: s[j] covers t-cols j*16+l15, j=0..7 ----
        f32x4 s[8] = {};
        #pragma unroll
        for (int ks = 0; ks < 2; ++ks) {
            unsigned soff = (unsigned)((((ks * 4) + l4) ^ l7) * 16);
            #pragma unroll
            for (int j = 0; j < 8; ++j) {
                bf16x8 kf = *(const bf16x8*)((const char*)Ks + (j*16 + l15) * 128 + soff);
                s[j] = __builtin_amdgcn_mfma_f32_16x16x32_bf16(qfr[ks], kf, s[j], 0, 0, 0);
            }
        }
        #pragma unroll
        for (int j = 0; j < 8; ++j) {
            int t = t0 + j * 16 + l15;
            if (t >= S_) { s[j][0] = -1e30f; s[j][1] = -1e30f; s[j][2] = -1e30f; s[j][3] = -1e30f; }
        }
        // ---- online softmax: max reduce, exp + P write (sums via MFMA below) ----
        float rm[4], sc[4];
        #pragma unroll
        for (int r = 0; r < 4; ++r) {
            rm[r] = fmaxf(fmaxf(s[0][r], s[1][r]), fmaxf(s[2][r], s[3][r]));
            rm[r] = fmaxf(rm[r], fmaxf(fmaxf(s[4][r], s[5][r]), fmaxf(s[6][r], s[7][r])));
        }
        #pragma unroll
        for (int mk = 1; mk <= 8; mk <<= 1) {
            #pragma unroll
            for (int r = 0; r < 4; ++r) rm[r] = fmaxf(rm[r], __shfl_xor(rm[r], mk));
        }
        #pragma unroll
        for (int r = 0; r < 4; ++r) {
            float mn = fmaxf(mreg[r], rm[r]);
            sc[r] = __expf(mreg[r] - mn);
            mreg[r] = mn;
        }
        #pragma unroll
        for (int j = 0; j < 8; ++j) {
            int inb = (j * 16 + l15) * 2;            // byte col in 256B row
            #pragma unroll
            for (int r = 0; r < 4; ++r) {
                float p = __expf(s[j][r] - mreg[r]);
                int row = l4 * 4 + r;
                *(unsigned short*)((char*)&Ps[w][0] + row * 256 +
                    ((((inb >> 4) ^ (row & 7)) << 4)) + (inb & 15)) = f2b(p);
            }
        }
        #pragma unroll
        for (int j = 0; j < 4; ++j) {
            accO[j][0] *= sc[0]; accO[j][1] *= sc[1];
            accO[j][2] *= sc[2]; accO[j][3] *= sc[3];
        }
        accS[0] *= sc[0]; accS[1] *= sc[1];
        accS[2] *= sc[2]; accS[3] *= sc[3];
        // ---- PV: A = Ps (16q x 128t), B = Vs (64d x 128t); 4 k-slices ----
        // plus B=ones fragment: accS[q-row] += sum_t P[q][t]
        #pragma unroll
        for (int ks = 0; ks < 4; ++ks) {
            unsigned soff = (unsigned)((((ks * 4) + l4) ^ l7) * 16);
            bf16x8 pf = *(const bf16x8*)((const char*)&Ps[w][0] + l15 * 256 + soff);
            #pragma unroll
            for (int j = 0; j < 4; ++j) {
                bf16x8 vf = *(const bf16x8*)((const char*)Vs + (j*16 + l15) * 256 + soff);
                accO[j] = __builtin_amdgcn_mfma_f32_16x16x32_bf16(pf, vf, accO[j], 0, 0, 0);
            }
            accS = __builtin_amdgcn_mfma_f32_16x16x32_bf16(pf, onesf, accS, 0, 0, 0);
        }
    }
    #pragma unroll
    for (int r = 0; r < 4; ++r) {
        int q = q0 + l4 * 4 + r;
        if (q >= S_) continue;
        float inv = 1.0f / accS[r];
        unsigned short* orow = o + ((size_t)q * B_ + b) * D_ + h * HD_;
        #pragma unroll
        for (int j = 0; j < 4; ++j)
            orow[j * 16 + l15] = f2b(accO[j][r] * inv);
    }
}

extern "C" void kernel_launch(void* const* d_in, const int* in_sizes, int n_in,
                              void* d_out, int out_size, void* d_ws, size_t ws_size,
                              hipStream_t stream) {
    const int*   tokens = (const int*)  d_in[0];
    const float* Wemb   = (const float*)d_in[1];
    const float* Wq     = (const float*)d_in[2];
    const float* bq     = (const float*)d_in[3];
    const float* Wk     = (const float*)d_in[4];
    const float* bk     = (const float*)d_in[5];
    const float* Wv     = (const float*)d_in[6];
    const float* bv     = (const float*)d_in[7];
    const float* Wo     = (const float*)d_in[8];
    const float* bo     = (const float*)d_in[9];
    const float* ln1g   = (const float*)d_in[10];
    const float* ln1b   = (const float*)d_in[11];
    const float* ln2g   = (const float*)d_in[12];
    const float* ln2b   = (const float*)d_in[13];
    const float* W1     = (const float*)d_in[14];
    const float* b1     = (const float*)d_in[15];
    const float* W2     = (const float*)d_in[16];
    const float* b2     = (const float*)d_in[17];
    const float* Wout   = (const float*)d_in[18];
    const float* bout   = (const float*)d_in[19];
    float* out = (float*)d_out;

    const size_t ND = (size_t)N_ * D_;
    const size_t NF = (size_t)N_ * FF_;
    const size_t M1 = (size_t)D_ * D_;
    const size_t M4 = (size_t)FF_ * D_;
    const size_t VT = (size_t)64 * 64 * 1024;

    float* x  = (float*)d_ws;
    unsigned short* hb = (unsigned short*)(x + ND);
    unsigned short* qb = hb + ND;
    unsigned short* kb = qb + ND;
    unsigned short* vb = kb + ND;
    unsigned short* ob = vb + ND;
    unsigned short* vt = ob + ND;
    unsigned short* f1 = vt + VT;
    unsigned short* wb = f1 + NF;           // 12M bf16 per-layer weights

    dim3 blk(256);
    embed_kernel<<<N_, blk, 0, stream>>>(tokens, Wemb, x);

    dim3 gQKV(16, 48);   // 256x64 tiles: M=4000->16, E=3072->48 (768 blocks)
    dim3 gW1(32, 64);    // 128x64 tiles: E=4096->64 (2048 blocks)
    dim3 gE64(32, 16);   // 128x64 tiles, E=1024->16 (512 blocks)
    dim3 gCv(12288);
    dim3 gVt(16, 64);
    dim3 gAt(16 * 64);   // 16 q-tiles of 64 x 64 (b,h)
    dim3 gOut((N_ + 63) / 64, 1);

    for (int l = 0; l < L_; ++l) {
        cvtw_kernel<<<gCv, blk, 0, stream>>>(Wq + l*M1, Wk + l*M1, Wv + l*M1,
                                             Wo + l*M1, W1 + l*M4, W2 + l*M4, wb);
        ln_kernel<<<N_, blk, 0, stream>>>(x, ln1g + l*D_, ln1b + l*D_, hb);
        ggemm_kernel<<<gQKV, dim3(512), 0, stream>>>(hb, wb,
            bq + l*D_, bk + l*D_, bv + l*D_, qb, kb, vb, N_, D_);
        vtr_kernel<<<gVt, blk, 0, stream>>>(vb, vt);
        mattn_kernel<<<gAt, blk, 0, stream>>>(qb, kb, vt, ob);
        dgemm_kernel<0><<<gE64, blk, 0, stream>>>(ob, wb + 3*M1,
            bo + l*D_, x, x, N_, D_);
        ln_kernel<<<N_, blk, 0, stream>>>(x, ln2g + l*D_, ln2b + l*D_, hb);
        dgemm_kernel<1><<<gW1, blk, 0, stream>>>(hb, wb + 4*M1,
            b1 + l*FF_, nullptr, f1, N_, D_);
        dgemm_kernel<0><<<gE64, blk, 0, stream>>>(f1, wb + 4*M1 + M4,
            b2 + l*D_, x, x, N_, FF_);
    }
    gemm_kernel<<<gOut, blk, 0, stream>>>(x, Wout, bout, out, N_, D_, 64);
}

// Round 20
// 1071.456 us; speedup vs baseline: 1.0488x; 1.0137x over previous
//
#include <hip/hip_runtime.h>
#include <hip/hip_bf16.h>
#include <math.h>

#define S_   1000
#define B_   4
#define D_   1024
#define H_   16
#define HD_  64
#define L_   4
#define FF_  4096
#define N_   (S_*B_)   /* 4000 token rows */

typedef __bf16 bf16x8 __attribute__((ext_vector_type(8)));
typedef float  f32x4  __attribute__((ext_vector_type(4)));
typedef __attribute__((address_space(3))) unsigned short lds_u16;

__device__ __forceinline__ unsigned short f2b(float f) {
    unsigned u = __builtin_bit_cast(unsigned, f);
    u = (u + 0x7FFFu + ((u >> 16) & 1u)) >> 16;   // RNE
    return (unsigned short)u;
}
__device__ __forceinline__ float b2f(unsigned short s) {
    unsigned u = (unsigned)s << 16;
    return __builtin_bit_cast(float, u);
}

__device__ __forceinline__ void gl16(const void* g, void* l) {
    __builtin_amdgcn_global_load_lds(
        (const __attribute__((address_space(1))) unsigned int*)g,
        (__attribute__((address_space(3))) unsigned int*)l, 16, 0, 0);
}

// inline-asm LDS read: invisible to compiler's mem-dep model, so it cannot
// auto-insert vmcnt(0) between global_load_lds and this read.
__device__ __forceinline__ bf16x8 ldsr(unsigned addr) {
    bf16x8 r;
    asm volatile("ds_read_b128 %0, %1" : "=v"(r) : "v"(addr));
    return r;
}

// ---------------- embedding lookup ----------------
__global__ void embed_kernel(const int* __restrict__ tokens,
                             const float* __restrict__ emb,
                             float* __restrict__ x) {
    int n = blockIdx.x;
    int tok = tokens[n];
    const float4* src = (const float4*)(emb + (size_t)tok * D_);
    float4* dst = (float4*)(x + (size_t)n * D_);
    dst[threadIdx.x] = src[threadIdx.x];
}

// ---------------- weight fp32->bf16 conversion (one layer, 12M elems) ----------------
__global__ __launch_bounds__(256)
void cvtw_kernel(const float* __restrict__ wq, const float* __restrict__ wk,
                 const float* __restrict__ wv, const float* __restrict__ wo,
                 const float* __restrict__ w1, const float* __restrict__ w2,
                 unsigned short* __restrict__ dst) {
    const size_t M1 = (size_t)D_ * D_;
    const size_t M4 = (size_t)FF_ * D_;
    size_t i = ((size_t)blockIdx.x * 256 + threadIdx.x) * 4;
    const float* src; size_t off;
    if      (i < M1)        { src = wq; off = i; }
    else if (i < 2*M1)      { src = wk; off = i - M1; }
    else if (i < 3*M1)      { src = wv; off = i - 2*M1; }
    else if (i < 4*M1)      { src = wo; off = i - 3*M1; }
    else if (i < 4*M1+M4)   { src = w1; off = i - 4*M1; }
    else                    { src = w2; off = i - 4*M1 - M4; }
    float4 v = *(const float4*)(src + off);
    ushort4 u;
    u.x = f2b(v.x); u.y = f2b(v.y); u.z = f2b(v.z); u.w = f2b(v.w);
    *(ushort4*)(dst + i) = u;
}

// ---------------- layernorm: fp32 in, bf16 out ----------------
__global__ __launch_bounds__(256)
void ln_kernel(const float* __restrict__ in,
               const float* __restrict__ g,
               const float* __restrict__ b,
               unsigned short* __restrict__ out) {
    int n = blockIdx.x;
    int tid = threadIdx.x;
    const float4* row = (const float4*)(in + (size_t)n * D_);
    float4 v = row[tid];
    float s  = v.x + v.y + v.z + v.w;
    float sq = v.x*v.x + v.y*v.y + v.z*v.z + v.w*v.w;
    #pragma unroll
    for (int off = 32; off; off >>= 1) {
        s  += __shfl_down(s, off);
        sq += __shfl_down(sq, off);
    }
    __shared__ float rs[4], rq[4];
    int wid = tid >> 6;
    if ((tid & 63) == 0) { rs[wid] = s; rq[wid] = sq; }
    __syncthreads();
    s  = rs[0] + rs[1] + rs[2] + rs[3];
    sq = rq[0] + rq[1] + rq[2] + rq[3];
    float mean = s * (1.0f / D_);
    float var  = sq * (1.0f / D_) - mean * mean;
    float rstd = rsqrtf(var + 1e-5f);
    float4 gg = ((const float4*)g)[tid];
    float4 bb = ((const float4*)b)[tid];
    ushort4 o;
    o.x = f2b((v.x - mean) * rstd * gg.x + bb.x);
    o.y = f2b((v.y - mean) * rstd * gg.y + bb.y);
    o.z = f2b((v.z - mean) * rstd * gg.z + bb.z);
    o.w = f2b((v.w - mean) * rstd * gg.w + bb.w);
    ((ushort4*)(out + (size_t)n * D_))[tid] = o;
}

// ---------------- 256x64 asm-ds_read 2-phase GEMM, 512 thr, wave tile 32x64 ----------------
// (round-14 proven) QKV split + fused RoPE — o0/o1/o2 bf16 stride 1024, q *0.125
__global__ __launch_bounds__(512, 4)
void ggemm_kernel(const unsigned short* __restrict__ A,
                  const unsigned short* __restrict__ W,
                  const float* __restrict__ bb0, const float* __restrict__ bb1,
                  const float* __restrict__ bb2,
                  unsigned short* __restrict__ o0, unsigned short* __restrict__ o1,
                  unsigned short* __restrict__ o2,
                  int M, int K) {
    __shared__ __align__(16) unsigned short As[2][256 * 64];   // 64 KB
    __shared__ __align__(16) unsigned short Bs[2][64 * 64];    // 16 KB
    int tid = threadIdx.x;
    int w = tid >> 6, lane = tid & 63;
    int m0 = blockIdx.x * 256, e0 = blockIdx.y * 64;
    int l15 = lane & 15, l4 = lane >> 4, l7 = lane & 7;

    f32x4 acc[2][4] = {};

    auto stage = [&](int buf, int kt) {
        #pragma unroll
        for (int rep = 0; rep < 4; ++rep) {
            int slot = rep * 512 + tid;            // A: 256 rows x 8 chunks
            int r = slot >> 3, c = slot & 7;
            int ar = m0 + r; if (ar > M - 1) ar = M - 1;
            gl16(A + (size_t)ar * K + kt + (c ^ (r & 7)) * 8, &As[buf][slot * 8]);
        }
        {
            int slot = tid;                        // B: 64 rows x 8 chunks
            int r = slot >> 3, c = slot & 7;
            gl16(W + (size_t)(e0 + r) * K + kt + (c ^ (r & 7)) * 8, &Bs[buf][slot * 8]);
        }
    };

    int aoff[2], boff[4];
    #pragma unroll
    for (int i = 0; i < 2; ++i) aoff[i] = (w * 32 + i * 16 + l15) * 128;
    #pragma unroll
    for (int j = 0; j < 4; ++j) boff[j] = (j * 16 + l15) * 128;

    stage(0, 0);
    asm volatile("s_waitcnt vmcnt(0)" ::: "memory");
    __builtin_amdgcn_sched_barrier(0);
    __builtin_amdgcn_s_barrier();

    int nk = K >> 6;
    for (int t = 0; t < nk; ++t) {
        int cur = t & 1;
        if (t + 1 < nk) stage(cur ^ 1, (t + 1) << 6);
        __builtin_amdgcn_sched_barrier(0);
        unsigned aB = (unsigned)(size_t)(lds_u16*)&As[cur][0];
        unsigned bB = (unsigned)(size_t)(lds_u16*)&Bs[cur][0];
        #pragma unroll
        for (int ks = 0; ks < 2; ++ks) {
            unsigned soff = (unsigned)((((ks * 4) + l4) ^ l7) * 16);
            bf16x8 av[2], bv[4];
            #pragma unroll
            for (int i = 0; i < 2; ++i) av[i] = ldsr(aB + aoff[i] + soff);
            #pragma unroll
            for (int j = 0; j < 4; ++j) bv[j] = ldsr(bB + boff[j] + soff);
            asm volatile("s_waitcnt lgkmcnt(0)" ::: "memory");
            __builtin_amdgcn_sched_barrier(0);
            __builtin_amdgcn_s_setprio(1);
            #pragma unroll
            for (int i = 0; i < 2; ++i)
                #pragma unroll
                for (int j = 0; j < 4; ++j)
                    acc[i][j] = __builtin_amdgcn_mfma_f32_16x16x32_bf16(av[i], bv[j], acc[i][j], 0, 0, 0);
            __builtin_amdgcn_s_setprio(0);
        }
        asm volatile("s_waitcnt vmcnt(0)" ::: "memory");
        __builtin_amdgcn_sched_barrier(0);
        __builtin_amdgcn_s_barrier();
    }

    // ---- epilogue (C/D: col=lane&15, row=(lane>>4)*4+reg) ----
    int sel = e0 >> 10;                     // 64-tile never crosses 1024 boundary
    int eobase = e0 & 1023;
    const float* bp = (sel == 0) ? bb0 : (sel == 1) ? bb1 : bb2;
    unsigned short* op = (sel == 0) ? o0 : (sel == 1) ? o1 : o2;
    if (sel == 2) {
        #pragma unroll
        for (int i = 0; i < 2; ++i) {
            int mrow = m0 + w*32 + i*16 + l4*4;
            #pragma unroll
            for (int j = 0; j < 4; ++j) {
                int eo = eobase + j*16 + l15;
                float bval = bp[eo];
                #pragma unroll
                for (int r = 0; r < 4; ++r) {
                    int m = mrow + r;
                    if (m >= M) continue;
                    op[(size_t)m * 1024 + eo] = f2b(acc[i][j][r] + bval);
                }
            }
        }
    } else {
        // fused RoPE: pair (d, d+32) = acc[i][jj], acc[i][jj+2]; rotate on fp32
        float scale = (sel == 0) ? 0.125f : 1.0f;
        #pragma unroll
        for (int i = 0; i < 2; ++i) {
            int mrow = m0 + w*32 + i*16 + l4*4;
            #pragma unroll
            for (int jj = 0; jj < 2; ++jj) {
                int d5 = jj*16 + l15;                 // 0..31 within head
                int eo_a = eobase + d5;
                int eo_b = eo_a + 32;
                float ba = bp[eo_a], bbv = bp[eo_b];
                float invf = __expf(-(float)d5 * 0.2878231366242557f); // ln(1e4)/32
                #pragma unroll
                for (int r = 0; r < 4; ++r) {
                    int m = mrow + r;
                    if (m >= M) continue;
                    int s = m >> 2;                   // n = s*B + b, B=4
                    float ang = (float)s * invf;
                    float sn, cs;
                    __sincosf(ang, &sn, &cs);
                    float a = acc[i][jj][r]   + ba;
                    float c = acc[i][jj+2][r] + bbv;
                    op[(size_t)m * 1024 + eo_a] = f2b((a*cs - c*sn) * scale);
                    op[(size_t)m * 1024 + eo_b] = f2b((c*cs + a*sn) * scale);
                }
            }
        }
    }
}

// ---------------- 128x64 asm-ds_read 2-phase GEMM (best per-FLOP structure) ----------------
// 4 waves 2x2, wave tile 64x32, 48 KB LDS -> 3 blocks/CU.
// MODE 0: +residual — out fp32 stride 1024
// MODE 1: GELU — out bf16 stride FF_
template<int MODE>
__global__ __launch_bounds__(256, 2)
void dgemm_kernel(const unsigned short* __restrict__ A,
                  const unsigned short* __restrict__ W,
                  const float* __restrict__ bias,
                  const float* __restrict__ res,
                  void* __restrict__ outv,
                  int M, int K) {
    __shared__ __align__(16) unsigned short As[2][128 * 64];   // 32 KB
    __shared__ __align__(16) unsigned short Bs[2][64 * 64];    // 16 KB
    int tid = threadIdx.x;
    int w = tid >> 6, lane = tid & 63;
    int wr = w >> 1, wc = w & 1;
    int m0 = blockIdx.x * 128, e0 = blockIdx.y * 64;
    int l15 = lane & 15, l4 = lane >> 4, l7 = lane & 7;

    f32x4 acc[4][2] = {};

    auto stage = [&](int buf, int kt) {
        #pragma unroll
        for (int rep = 0; rep < 4; ++rep) {
            int slot = rep * 256 + tid;            // A: 128 rows
            int r = slot >> 3, c = slot & 7;
            int ar = m0 + r; if (ar > M - 1) ar = M - 1;
            gl16(A + (size_t)ar * K + kt + (c ^ (r & 7)) * 8, &As[buf][slot * 8]);
        }
        #pragma unroll
        for (int rep = 0; rep < 2; ++rep) {
            int slot = rep * 256 + tid;            // B: 64 rows
            int r = slot >> 3, c = slot & 7;
            gl16(W + (size_t)(e0 + r) * K + kt + (c ^ (r & 7)) * 8, &Bs[buf][slot * 8]);
        }
    };

    int aoff[4], boff[2];
    #pragma unroll
    for (int i = 0; i < 4; ++i) aoff[i] = (wr * 64 + i * 16 + l15) * 128;
    #pragma unroll
    for (int j = 0; j < 2; ++j) boff[j] = (wc * 32 + j * 16 + l15) * 128;

    stage(0, 0);
    asm volatile("s_waitcnt vmcnt(0)" ::: "memory");
    __builtin_amdgcn_sched_barrier(0);
    __builtin_amdgcn_s_barrier();

    int nk = K >> 6;
    for (int t = 0; t < nk; ++t) {
        int cur = t & 1;
        if (t + 1 < nk) stage(cur ^ 1, (t + 1) << 6);
        __builtin_amdgcn_sched_barrier(0);
        unsigned aB = (unsigned)(size_t)(lds_u16*)&As[cur][0];
        unsigned bB = (unsigned)(size_t)(lds_u16*)&Bs[cur][0];
        #pragma unroll
        for (int ks = 0; ks < 2; ++ks) {
            unsigned soff = (unsigned)((((ks * 4) + l4) ^ l7) * 16);
            bf16x8 av[4], bv[2];
            #pragma unroll
            for (int i = 0; i < 4; ++i) av[i] = ldsr(aB + aoff[i] + soff);
            #pragma unroll
            for (int j = 0; j < 2; ++j) bv[j] = ldsr(bB + boff[j] + soff);
            asm volatile("s_waitcnt lgkmcnt(0)" ::: "memory");
            __builtin_amdgcn_sched_barrier(0);
            __builtin_amdgcn_s_setprio(1);
            #pragma unroll
            for (int i = 0; i < 4; ++i)
                #pragma unroll
                for (int j = 0; j < 2; ++j)
                    acc[i][j] = __builtin_amdgcn_mfma_f32_16x16x32_bf16(av[i], bv[j], acc[i][j], 0, 0, 0);
            __builtin_amdgcn_s_setprio(0);
        }
        asm volatile("s_waitcnt vmcnt(0)" ::: "memory");
        __builtin_amdgcn_sched_barrier(0);
        __builtin_amdgcn_s_barrier();
    }

    if (MODE == 0) {
        float* out = (float*)outv;
        #pragma unroll
        for (int i = 0; i < 4; ++i) {
            int mrow = m0 + wr*64 + i*16 + l4*4;
            #pragma unroll
            for (int j = 0; j < 2; ++j) {
                int e = e0 + wc*32 + j*16 + l15;
                float bval = bias[e];
                #pragma unroll
                for (int r = 0; r < 4; ++r) {
                    int m = mrow + r;
                    if (m >= M) continue;
                    out[(size_t)m * 1024 + e] = acc[i][j][r] + bval + res[(size_t)m * 1024 + e];
                }
            }
        }
    } else {
        unsigned short* out = (unsigned short*)outv;
        #pragma unroll
        for (int i = 0; i < 4; ++i) {
            int mrow = m0 + wr*64 + i*16 + l4*4;
            #pragma unroll
            for (int j = 0; j < 2; ++j) {
                int e = e0 + wc*32 + j*16 + l15;
                float bval = bias[e];
                #pragma unroll
                for (int r = 0; r < 4; ++r) {
                    int m = mrow + r;
                    if (m >= M) continue;
                    float val = acc[i][j][r] + bval;
                    val = 0.5f * val * (1.0f + erff(val * 0.70710678118654752f));
                    out[(size_t)m * FF_ + e] = f2b(val);
                }
            }
        }
    }
}

// ---------------- fp32 tiled GEMM (final 64-col projection only) ----------------
__global__ __launch_bounds__(256)
void gemm_kernel(const float* __restrict__ A, const float* __restrict__ W,
                 const float* __restrict__ bias, float* __restrict__ C,
                 int M, int K, int E) {
    __shared__ float As[32][64];
    __shared__ float Ws[32][64];
    int tid = threadIdx.x;
    int m0 = blockIdx.x * 64, e0 = blockIdx.y * 64;
    int tx = tid & 15, ty = tid >> 4;
    int lrow = tid >> 2;
    int lkc  = (tid & 3) * 8;
    float acc[4][4] = {};
    const float* Arow = A + (size_t)(m0 + lrow) * K + lkc;
    const float* Wrow = W + (size_t)(e0 + lrow) * K + lkc;
    bool aval = (m0 + lrow) < M;

    for (int k0 = 0; k0 < K; k0 += 32) {
        float4 a0 = make_float4(0.f,0.f,0.f,0.f), a1 = a0;
        if (aval) {
            a0 = *(const float4*)(Arow + k0);
            a1 = *(const float4*)(Arow + k0 + 4);
        }
        float4 w0 = *(const float4*)(Wrow + k0);
        float4 w1 = *(const float4*)(Wrow + k0 + 4);
        As[lkc+0][lrow] = a0.x; As[lkc+1][lrow] = a0.y;
        As[lkc+2][lrow] = a0.z; As[lkc+3][lrow] = a0.w;
        As[lkc+4][lrow] = a1.x; As[lkc+5][lrow] = a1.y;
        As[lkc+6][lrow] = a1.z; As[lkc+7][lrow] = a1.w;
        Ws[lkc+0][lrow] = w0.x; Ws[lkc+1][lrow] = w0.y;
        Ws[lkc+2][lrow] = w0.z; Ws[lkc+3][lrow] = w0.w;
        Ws[lkc+4][lrow] = w1.x; Ws[lkc+5][lrow] = w1.y;
        Ws[lkc+6][lrow] = w1.z; Ws[lkc+7][lrow] = w1.w;
        __syncthreads();
        #pragma unroll
        for (int kk = 0; kk < 32; ++kk) {
            float4 a = *(const float4*)(&As[kk][ty*4]);
            float4 ww = *(const float4*)(&Ws[kk][tx*4]);
            acc[0][0] += a.x*ww.x; acc[0][1] += a.x*ww.y; acc[0][2] += a.x*ww.z; acc[0][3] += a.x*ww.w;
            acc[1][0] += a.y*ww.x; acc[1][1] += a.y*ww.y; acc[1][2] += a.y*ww.z; acc[1][3] += a.y*ww.w;
            acc[2][0] += a.z*ww.x; acc[2][1] += a.z*ww.y; acc[2][2] += a.z*ww.z; acc[2][3] += a.z*ww.w;
            acc[3][0] += a.w*ww.x; acc[3][1] += a.w*ww.y; acc[3][2] += a.w*ww.z; acc[3][3] += a.w*ww.w;
        }
        __syncthreads();
    }
    #pragma unroll
    for (int i = 0; i < 4; ++i) {
        int m = m0 + ty*4 + i;
        if (m >= M) continue;
        #pragma unroll
        for (int j = 0; j < 4; ++j) {
            int e = e0 + tx*4 + j;
            C[(size_t)m * E + e] = acc[i][j] + bias[e];
        }
    }
}

// ---------------- V transpose: [s][b][h*64+d] bf16 -> [bh][d][1024] bf16 ----------------
__global__ __launch_bounds__(256)
void vtr_kernel(const unsigned short* __restrict__ vin,
                unsigned short* __restrict__ vout) {
    __shared__ unsigned short T[64][65];
    int tt = blockIdx.x;
    int bh = blockIdx.y;
    int b = bh >> 4, h = bh & 15;
    int tid = threadIdx.x;
    #pragma unroll
    for (int rep = 0; rep < 2; ++rep) {
        int slot = rep * 256 + tid;
        int r = slot >> 3, ch = slot & 7;
        int t = tt * 64 + r;
        unsigned short e[8] = {0,0,0,0,0,0,0,0};
        if (t < S_) {
            const unsigned short* src = vin + ((size_t)t * B_ + b) * D_ + h * HD_ + ch * 8;
            *(ushort4*)&e[0] = *(const ushort4*)(src);
            *(ushort4*)&e[4] = *(const ushort4*)(src + 4);
        }
        #pragma unroll
        for (int u = 0; u < 8; ++u) T[r][ch*8+u] = e[u];
    }
    __syncthreads();
    #pragma unroll
    for (int rep = 0; rep < 2; ++rep) {
        int slot = rep * 256 + tid;
        int d = slot >> 3, ch = slot & 7;
        unsigned short e[8];
        #pragma unroll
        for (int u = 0; u < 8; ++u) e[u] = T[ch*8+u][d];
        unsigned short* dst = vout + ((size_t)bh * 64 + d) * 1024 + tt * 64 + ch * 8;
        *(ushort4*)(dst)     = *(ushort4*)&e[0];
        *(ushort4*)(dst + 4) = *(ushort4*)&e[4];
    }
}

// ---------------- bf16 MFMA flash attention: 64 q x (b,h), KVBLK=128 ----------------
// 256 thr / 4 waves x 16 q-rows. Row sums on the matrix pipe (accS = mfma(P,
// ones), same rescale recurrence as lreg). This round: T5 setprio around both
// MFMA clusters (independent blocks, 3/CU — m191's regime), and native __bf16
// casts for the 32 P conversions/thread/tile (1 v_cvt vs 4-op hand-RNE).
// LDS 48 KB: Ks[128][64] 16K + Vs[64][128] 16K + Ps[4][16][128] 16K -> 3 blk/CU.
__global__ __launch_bounds__(256)
void mattn_kernel(const unsigned short* __restrict__ qg,
                  const unsigned short* __restrict__ kg,
                  const unsigned short* __restrict__ vt,
                  unsigned short* __restrict__ o) {
    __shared__ __align__(16) unsigned short Ks[128 * 64];
    __shared__ __align__(16) unsigned short Vs[64 * 128];
    __shared__ __align__(16) unsigned short Ps[4][16 * 128];

    int bid = blockIdx.x;
    int qt = bid & 15;
    int bh = bid >> 4;
    int b = bh >> 4, h = bh & 15;
    int tid = threadIdx.x;
    int w = tid >> 6, lane = tid & 63;
    int l15 = lane & 15, l4 = lane >> 4, l7 = lane & 7;
    int q0 = qt * 64 + w * 16;

    bf16x8 qfr[2];
    {
        int qr = q0 + l15; if (qr > S_ - 1) qr = S_ - 1;
        const unsigned short* qrow = qg + ((size_t)qr * B_ + b) * D_ + h * HD_;
        qfr[0] = *(const bf16x8*)(qrow + l4 * 8);
        qfr[1] = *(const bf16x8*)(qrow + 32 + l4 * 8);
    }
    bf16x8 onesf;
    #pragma unroll
    for (int z = 0; z < 8; ++z) onesf[z] = (__bf16)1.0f;

    f32x4 accO[4] = {};
    f32x4 accS = {0.f, 0.f, 0.f, 0.f};          // MFMA-computed row sums
    float mreg[4] = {-1e30f, -1e30f, -1e30f, -1e30f};

    for (int t0 = 0; t0 < 1024; t0 += 128) {
        __syncthreads();
        // stage K: 128 rows x 8 chunks (1024 slots, 4/thread)
        #pragma unroll
        for (int rep = 0; rep < 4; ++rep) {
            int slot = rep * 256 + tid;
            int r = slot >> 3, c = slot & 7;
            int tr = t0 + r; if (tr > S_ - 1) tr = S_ - 1;
            gl16(kg + ((size_t)tr * B_ + b) * D_ + h * HD_ + (c ^ (r & 7)) * 8,
                 &Ks[slot * 8]);
        }
        // stage V: 64 d-rows x 16 chunks (1024 slots, 4/thread)
        #pragma unroll
        for (int rep = 0; rep < 4; ++rep) {
            int slot = rep * 256 + tid;
            int r = slot >> 4, c = slot & 15;
            gl16(vt + ((size_t)bh * 64 + r) * 1024 + t0 + (c ^ (r & 7)) * 8,
                 &Vs[slot * 8]);
        }
        __syncthreads();

        // ---- QK^T: s[j] covers t-cols j*16+l15, j=0..7 ----
        f32x4 s[8] = {};
        __builtin_amdgcn_s_setprio(1);
        #pragma unroll
        for (int ks = 0; ks < 2; ++ks) {
            unsigned soff = (unsigned)((((ks * 4) + l4) ^ l7) * 16);
            #pragma unroll
            for (int j = 0; j < 8; ++j) {
                bf16x8 kf = *(const bf16x8*)((const char*)Ks + (j*16 + l15) * 128 + soff);
                s[j] = __builtin_amdgcn_mfma_f32_16x16x32_bf16(qfr[ks], kf, s[j], 0, 0, 0);
            }
        }
        __builtin_amdgcn_s_setprio(0);
        #pragma unroll
        for (int j = 0; j < 8; ++j) {
            int t = t0 + j * 16 + l15;
            if (t >= S_) { s[j][0] = -1e30f; s[j][1] = -1e30f; s[j][2] = -1e30f; s[j][3] = -1e30f; }
        }
        // ---- online softmax: max reduce, exp + P write (sums via MFMA below) ----
        float rm[4], sc[4];
        #pragma unroll
        for (int r = 0; r < 4; ++r) {
            rm[r] = fmaxf(fmaxf(s[0][r], s[1][r]), fmaxf(s[2][r], s[3][r]));
            rm[r] = fmaxf(rm[r], fmaxf(fmaxf(s[4][r], s[5][r]), fmaxf(s[6][r], s[7][r])));
        }
        #pragma unroll
        for (int mk = 1; mk <= 8; mk <<= 1) {
            #pragma unroll
            for (int r = 0; r < 4; ++r) rm[r] = fmaxf(rm[r], __shfl_xor(rm[r], mk));
        }
        #pragma unroll
        for (int r = 0; r < 4; ++r) {
            float mn = fmaxf(mreg[r], rm[r]);
            sc[r] = __expf(mreg[r] - mn);
            mreg[r] = mn;
        }
        #pragma unroll
        for (int j = 0; j < 8; ++j) {
            int inb = (j * 16 + l15) * 2;            // byte col in 256B row
            #pragma unroll
            for (int r = 0; r < 4; ++r) {
                float p = __expf(s[j][r] - mreg[r]);
                int row = l4 * 4 + r;
                *(__bf16*)((char*)&Ps[w][0] + row * 256 +
                    ((((inb >> 4) ^ (row & 7)) << 4)) + (inb & 15)) = (__bf16)p;
            }
        }
        #pragma unroll
        for (int j = 0; j < 4; ++j) {
            accO[j][0] *= sc[0]; accO[j][1] *= sc[1];
            accO[j][2] *= sc[2]; accO[j][3] *= sc[3];
        }
        accS[0] *= sc[0]; accS[1] *= sc[1];
        accS[2] *= sc[2]; accS[3] *= sc[3];
        // ---- PV: A = Ps (16q x 128t), B = Vs (64d x 128t); 4 k-slices ----
        // plus B=ones fragment: accS[q-row] += sum_t P[q][t]
        __builtin_amdgcn_s_setprio(1);
        #pragma unroll
        for (int ks = 0; ks < 4; ++ks) {
            unsigned soff = (unsigned)((((ks * 4) + l4) ^ l7) * 16);
            bf16x8 pf = *(const bf16x8*)((const char*)&Ps[w][0] + l15 * 256 + soff);
            #pragma unroll
            for (int j = 0; j < 4; ++j) {
                bf16x8 vf = *(const bf16x8*)((const char*)Vs + (j*16 + l15) * 256 + soff);
                accO[j] = __builtin_amdgcn_mfma_f32_16x16x32_bf16(pf, vf, accO[j], 0, 0, 0);
            }
            accS = __builtin_amdgcn_mfma_f32_16x16x32_bf16(pf, onesf, accS, 0, 0, 0);
        }
        __builtin_amdgcn_s_setprio(0);
    }
    #pragma unroll
    for (int r = 0; r < 4; ++r) {
        int q = q0 + l4 * 4 + r;
        if (q >= S_) continue;
        float inv = 1.0f / accS[r];
        unsigned short* orow = o + ((size_t)q * B_ + b) * D_ + h * HD_;
        #pragma unroll
        for (int j = 0; j < 4; ++j)
            orow[j * 16 + l15] = f2b(accO[j][r] * inv);
    }
}

extern "C" void kernel_launch(void* const* d_in, const int* in_sizes, int n_in,
                              void* d_out, int out_size, void* d_ws, size_t ws_size,
                              hipStream_t stream) {
    const int*   tokens = (const int*)  d_in[0];
    const float* Wemb   = (const float*)d_in[1];
    const float* Wq     = (const float*)d_in[2];
    const float* bq     = (const float*)d_in[3];
    const float* Wk     = (const float*)d_in[4];
    const float* bk     = (const float*)d_in[5];
    const float* Wv     = (const float*)d_in[6];
    const float* bv     = (const float*)d_in[7];
    const float* Wo     = (const float*)d_in[8];
    const float* bo     = (const float*)d_in[9];
    const float* ln1g   = (const float*)d_in[10];
    const float* ln1b   = (const float*)d_in[11];
    const float* ln2g   = (const float*)d_in[12];
    const float* ln2b   = (const float*)d_in[13];
    const float* W1     = (const float*)d_in[14];
    const float* b1     = (const float*)d_in[15];
    const float* W2     = (const float*)d_in[16];
    const float* b2     = (const float*)d_in[17];
    const float* Wout   = (const float*)d_in[18];
    const float* bout   = (const float*)d_in[19];
    float* out = (float*)d_out;

    const size_t ND = (size_t)N_ * D_;
    const size_t NF = (size_t)N_ * FF_;
    const size_t M1 = (size_t)D_ * D_;
    const size_t M4 = (size_t)FF_ * D_;
    const size_t VT = (size_t)64 * 64 * 1024;

    float* x  = (float*)d_ws;
    unsigned short* hb = (unsigned short*)(x + ND);
    unsigned short* qb = hb + ND;
    unsigned short* kb = qb + ND;
    unsigned short* vb = kb + ND;
    unsigned short* ob = vb + ND;
    unsigned short* vt = ob + ND;
    unsigned short* f1 = vt + VT;
    unsigned short* wb = f1 + NF;           // 12M bf16 per-layer weights

    dim3 blk(256);
    embed_kernel<<<N_, blk, 0, stream>>>(tokens, Wemb, x);

    dim3 gQKV(16, 48);   // 256x64 tiles: M=4000->16, E=3072->48 (768 blocks)
    dim3 gW1(32, 64);    // 128x64 tiles: E=4096->64 (2048 blocks)
    dim3 gE64(32, 16);   // 128x64 tiles, E=1024->16 (512 blocks)
    dim3 gCv(12288);
    dim3 gVt(16, 64);
    dim3 gAt(16 * 64);   // 16 q-tiles of 64 x 64 (b,h)
    dim3 gOut((N_ + 63) / 64, 1);

    for (int l = 0; l < L_; ++l) {
        cvtw_kernel<<<gCv, blk, 0, stream>>>(Wq + l*M1, Wk + l*M1, Wv + l*M1,
                                             Wo + l*M1, W1 + l*M4, W2 + l*M4, wb);
        ln_kernel<<<N_, blk, 0, stream>>>(x, ln1g + l*D_, ln1b + l*D_, hb);
        ggemm_kernel<<<gQKV, dim3(512), 0, stream>>>(hb, wb,
            bq + l*D_, bk + l*D_, bv + l*D_, qb, kb, vb, N_, D_);
        vtr_kernel<<<gVt, blk, 0, stream>>>(vb, vt);
        mattn_kernel<<<gAt, blk, 0, stream>>>(qb, kb, vt, ob);
        dgemm_kernel<0><<<gE64, blk, 0, stream>>>(ob, wb + 3*M1,
            bo + l*D_, x, x, N_, D_);
        ln_kernel<<<N_, blk, 0, stream>>>(x, ln2g + l*D_, ln2b + l*D_, hb);
        dgemm_kernel<1><<<gW1, blk, 0, stream>>>(hb, wb + 4*M1,
            b1 + l*FF_, nullptr, f1, N_, D_);
        dgemm_kernel<0><<<gE64, blk, 0, stream>>>(f1, wb + 4*M1 + M4,
            b2 + l*D_, x, x, N_, FF_);
    }
    gemm_kernel<<<gOut, blk, 0, stream>>>(x, Wout, bout, out, N_, D_, 64);
}

// Round 21
// 1062.382 us; speedup vs baseline: 1.0578x; 1.0085x over previous
//
#include <hip/hip_runtime.h>
#include <hip/hip_bf16.h>
#include <math.h>

#define S_   1000
#define B_   4
#define D_   1024
#define H_   16
#define HD_  64
#define L_   4
#define FF_  4096
#define N_   (S_*B_)   /* 4000 token rows */

typedef __bf16 bf16x8 __attribute__((ext_vector_type(8)));
typedef float  f32x4  __attribute__((ext_vector_type(4)));
typedef __attribute__((address_space(3))) unsigned short lds_u16;

__device__ __forceinline__ unsigned short f2b(float f) {
    unsigned u = __builtin_bit_cast(unsigned, f);
    u = (u + 0x7FFFu + ((u >> 16) & 1u)) >> 16;   // RNE
    return (unsigned short)u;
}
__device__ __forceinline__ float b2f(unsigned short s) {
    unsigned u = (unsigned)s << 16;
    return __builtin_bit_cast(float, u);
}

__device__ __forceinline__ void gl16(const void* g, void* l) {
    __builtin_amdgcn_global_load_lds(
        (const __attribute__((address_space(1))) unsigned int*)g,
        (__attribute__((address_space(3))) unsigned int*)l, 16, 0, 0);
}

// inline-asm LDS read: invisible to compiler's mem-dep model, so it cannot
// auto-insert vmcnt(0) between global_load_lds and this read.
__device__ __forceinline__ bf16x8 ldsr(unsigned addr) {
    bf16x8 r;
    asm volatile("ds_read_b128 %0, %1" : "=v"(r) : "v"(addr));
    return r;
}

// ---------------- embedding lookup ----------------
__global__ void embed_kernel(const int* __restrict__ tokens,
                             const float* __restrict__ emb,
                             float* __restrict__ x) {
    int n = blockIdx.x;
    int tok = tokens[n];
    const float4* src = (const float4*)(emb + (size_t)tok * D_);
    float4* dst = (float4*)(x + (size_t)n * D_);
    dst[threadIdx.x] = src[threadIdx.x];
}

// ---------------- weight fp32->bf16 conversion (one layer, 12M elems) ----------------
__global__ __launch_bounds__(256)
void cvtw_kernel(const float* __restrict__ wq, const float* __restrict__ wk,
                 const float* __restrict__ wv, const float* __restrict__ wo,
                 const float* __restrict__ w1, const float* __restrict__ w2,
                 unsigned short* __restrict__ dst) {
    const size_t M1 = (size_t)D_ * D_;
    const size_t M4 = (size_t)FF_ * D_;
    size_t i = ((size_t)blockIdx.x * 256 + threadIdx.x) * 4;
    const float* src; size_t off;
    if      (i < M1)        { src = wq; off = i; }
    else if (i < 2*M1)      { src = wk; off = i - M1; }
    else if (i < 3*M1)      { src = wv; off = i - 2*M1; }
    else if (i < 4*M1)      { src = wo; off = i - 3*M1; }
    else if (i < 4*M1+M4)   { src = w1; off = i - 4*M1; }
    else                    { src = w2; off = i - 4*M1 - M4; }
    float4 v = *(const float4*)(src + off);
    ushort4 u;
    u.x = f2b(v.x); u.y = f2b(v.y); u.z = f2b(v.z); u.w = f2b(v.w);
    *(ushort4*)(dst + i) = u;
}

// ---------------- layernorm: fp32 in, bf16 out ----------------
__global__ __launch_bounds__(256)
void ln_kernel(const float* __restrict__ in,
               const float* __restrict__ g,
               const float* __restrict__ b,
               unsigned short* __restrict__ out) {
    int n = blockIdx.x;
    int tid = threadIdx.x;
    const float4* row = (const float4*)(in + (size_t)n * D_);
    float4 v = row[tid];
    float s  = v.x + v.y + v.z + v.w;
    float sq = v.x*v.x + v.y*v.y + v.z*v.z + v.w*v.w;
    #pragma unroll
    for (int off = 32; off; off >>= 1) {
        s  += __shfl_down(s, off);
        sq += __shfl_down(sq, off);
    }
    __shared__ float rs[4], rq[4];
    int wid = tid >> 6;
    if ((tid & 63) == 0) { rs[wid] = s; rq[wid] = sq; }
    __syncthreads();
    s  = rs[0] + rs[1] + rs[2] + rs[3];
    sq = rq[0] + rq[1] + rq[2] + rq[3];
    float mean = s * (1.0f / D_);
    float var  = sq * (1.0f / D_) - mean * mean;
    float rstd = rsqrtf(var + 1e-5f);
    float4 gg = ((const float4*)g)[tid];
    float4 bb = ((const float4*)b)[tid];
    ushort4 o;
    o.x = f2b((v.x - mean) * rstd * gg.x + bb.x);
    o.y = f2b((v.y - mean) * rstd * gg.y + bb.y);
    o.z = f2b((v.z - mean) * rstd * gg.z + bb.z);
    o.w = f2b((v.w - mean) * rstd * gg.w + bb.w);
    ((ushort4*)(out + (size_t)n * D_))[tid] = o;
}

// ---------------- 256x64 tail-staged counted-vmcnt GEMM, 512 thr, wave tile 32x64 ----------------
// QKV split + fused RoPE. Stage = 5 gl16/thread. Prologue stages tiles 0,1;
// iter t: vmcnt(5) [tile t landed, t+1 in flight] -> barrier -> asm ds_read +
// MFMA -> lgkm(0) -> barrier -> stage tile t+2 into the just-freed buffer.
// Lead for tile t+2 = one full iteration; queue never drains in main loop.
__global__ __launch_bounds__(512, 4)
void ggemm_kernel(const unsigned short* __restrict__ A,
                  const unsigned short* __restrict__ W,
                  const float* __restrict__ bb0, const float* __restrict__ bb1,
                  const float* __restrict__ bb2,
                  unsigned short* __restrict__ o0, unsigned short* __restrict__ o1,
                  unsigned short* __restrict__ o2,
                  int M, int K) {
    __shared__ __align__(16) unsigned short As[2][256 * 64];   // 64 KB
    __shared__ __align__(16) unsigned short Bs[2][64 * 64];    // 16 KB
    int tid = threadIdx.x;
    int w = tid >> 6, lane = tid & 63;
    int m0 = blockIdx.x * 256, e0 = blockIdx.y * 64;
    int l15 = lane & 15, l4 = lane >> 4, l7 = lane & 7;

    f32x4 acc[2][4] = {};

    auto stage = [&](int buf, int kt) {
        #pragma unroll
        for (int rep = 0; rep < 4; ++rep) {
            int slot = rep * 512 + tid;            // A: 256 rows x 8 chunks
            int r = slot >> 3, c = slot & 7;
            int ar = m0 + r; if (ar > M - 1) ar = M - 1;
            gl16(A + (size_t)ar * K + kt + (c ^ (r & 7)) * 8, &As[buf][slot * 8]);
        }
        {
            int slot = tid;                        // B: 64 rows x 8 chunks
            int r = slot >> 3, c = slot & 7;
            gl16(W + (size_t)(e0 + r) * K + kt + (c ^ (r & 7)) * 8, &Bs[buf][slot * 8]);
        }
    };

    int aoff[2], boff[4];
    #pragma unroll
    for (int i = 0; i < 2; ++i) aoff[i] = (w * 32 + i * 16 + l15) * 128;
    #pragma unroll
    for (int j = 0; j < 4; ++j) boff[j] = (j * 16 + l15) * 128;

    int nk = K >> 6;
    stage(0, 0);
    if (nk > 1) stage(1, 64);
    for (int t = 0; t < nk; ++t) {
        int cur = t & 1;
        if (t + 1 < nk) {
            asm volatile("s_waitcnt vmcnt(5)" ::: "memory");   // tile t landed
        } else {
            asm volatile("s_waitcnt vmcnt(0)" ::: "memory");
        }
        __builtin_amdgcn_sched_barrier(0);
        __builtin_amdgcn_s_barrier();
        unsigned aB = (unsigned)(size_t)(lds_u16*)&As[cur][0];
        unsigned bB = (unsigned)(size_t)(lds_u16*)&Bs[cur][0];
        #pragma unroll
        for (int ks = 0; ks < 2; ++ks) {
            unsigned soff = (unsigned)((((ks * 4) + l4) ^ l7) * 16);
            bf16x8 av[2], bv[4];
            #pragma unroll
            for (int i = 0; i < 2; ++i) av[i] = ldsr(aB + aoff[i] + soff);
            #pragma unroll
            for (int j = 0; j < 4; ++j) bv[j] = ldsr(bB + boff[j] + soff);
            asm volatile("s_waitcnt lgkmcnt(0)" ::: "memory");
            __builtin_amdgcn_sched_barrier(0);
            __builtin_amdgcn_s_setprio(1);
            #pragma unroll
            for (int i = 0; i < 2; ++i)
                #pragma unroll
                for (int j = 0; j < 4; ++j)
                    acc[i][j] = __builtin_amdgcn_mfma_f32_16x16x32_bf16(av[i], bv[j], acc[i][j], 0, 0, 0);
            __builtin_amdgcn_s_setprio(0);
        }
        asm volatile("s_waitcnt lgkmcnt(0)" ::: "memory");     // reads of buf[cur] done
        __builtin_amdgcn_sched_barrier(0);
        __builtin_amdgcn_s_barrier();
        if (t + 2 < nk) stage(cur, (t + 2) << 6);              // overwrite freed buffer
    }

    // ---- epilogue (C/D: col=lane&15, row=(lane>>4)*4+reg) ----
    int sel = e0 >> 10;                     // 64-tile never crosses 1024 boundary
    int eobase = e0 & 1023;
    const float* bp = (sel == 0) ? bb0 : (sel == 1) ? bb1 : bb2;
    unsigned short* op = (sel == 0) ? o0 : (sel == 1) ? o1 : o2;
    if (sel == 2) {
        #pragma unroll
        for (int i = 0; i < 2; ++i) {
            int mrow = m0 + w*32 + i*16 + l4*4;
            #pragma unroll
            for (int j = 0; j < 4; ++j) {
                int eo = eobase + j*16 + l15;
                float bval = bp[eo];
                #pragma unroll
                for (int r = 0; r < 4; ++r) {
                    int m = mrow + r;
                    if (m >= M) continue;
                    op[(size_t)m * 1024 + eo] = f2b(acc[i][j][r] + bval);
                }
            }
        }
    } else {
        // fused RoPE: pair (d, d+32) = acc[i][jj], acc[i][jj+2]; rotate on fp32
        float scale = (sel == 0) ? 0.125f : 1.0f;
        #pragma unroll
        for (int i = 0; i < 2; ++i) {
            int mrow = m0 + w*32 + i*16 + l4*4;
            #pragma unroll
            for (int jj = 0; jj < 2; ++jj) {
                int d5 = jj*16 + l15;                 // 0..31 within head
                int eo_a = eobase + d5;
                int eo_b = eo_a + 32;
                float ba = bp[eo_a], bbv = bp[eo_b];
                float invf = __expf(-(float)d5 * 0.2878231366242557f); // ln(1e4)/32
                #pragma unroll
                for (int r = 0; r < 4; ++r) {
                    int m = mrow + r;
                    if (m >= M) continue;
                    int s = m >> 2;                   // n = s*B + b, B=4
                    float ang = (float)s * invf;
                    float sn, cs;
                    __sincosf(ang, &sn, &cs);
                    float a = acc[i][jj][r]   + ba;
                    float c = acc[i][jj+2][r] + bbv;
                    op[(size_t)m * 1024 + eo_a] = f2b((a*cs - c*sn) * scale);
                    op[(size_t)m * 1024 + eo_b] = f2b((c*cs + a*sn) * scale);
                }
            }
        }
    }
}

// ---------------- 128x64 tail-staged counted-vmcnt GEMM ----------------
// 4 waves 2x2, wave tile 64x32, 48 KB LDS -> 3 blocks/CU. Stage = 6 gl16/thr.
// MODE 0: +residual — out fp32 stride 1024
// MODE 1: GELU — out bf16 stride FF_
template<int MODE>
__global__ __launch_bounds__(256, 2)
void dgemm_kernel(const unsigned short* __restrict__ A,
                  const unsigned short* __restrict__ W,
                  const float* __restrict__ bias,
                  const float* __restrict__ res,
                  void* __restrict__ outv,
                  int M, int K) {
    __shared__ __align__(16) unsigned short As[2][128 * 64];   // 32 KB
    __shared__ __align__(16) unsigned short Bs[2][64 * 64];    // 16 KB
    int tid = threadIdx.x;
    int w = tid >> 6, lane = tid & 63;
    int wr = w >> 1, wc = w & 1;
    int m0 = blockIdx.x * 128, e0 = blockIdx.y * 64;
    int l15 = lane & 15, l4 = lane >> 4, l7 = lane & 7;

    f32x4 acc[4][2] = {};

    auto stage = [&](int buf, int kt) {
        #pragma unroll
        for (int rep = 0; rep < 4; ++rep) {
            int slot = rep * 256 + tid;            // A: 128 rows
            int r = slot >> 3, c = slot & 7;
            int ar = m0 + r; if (ar > M - 1) ar = M - 1;
            gl16(A + (size_t)ar * K + kt + (c ^ (r & 7)) * 8, &As[buf][slot * 8]);
        }
        #pragma unroll
        for (int rep = 0; rep < 2; ++rep) {
            int slot = rep * 256 + tid;            // B: 64 rows
            int r = slot >> 3, c = slot & 7;
            gl16(W + (size_t)(e0 + r) * K + kt + (c ^ (r & 7)) * 8, &Bs[buf][slot * 8]);
        }
    };

    int aoff[4], boff[2];
    #pragma unroll
    for (int i = 0; i < 4; ++i) aoff[i] = (wr * 64 + i * 16 + l15) * 128;
    #pragma unroll
    for (int j = 0; j < 2; ++j) boff[j] = (wc * 32 + j * 16 + l15) * 128;

    int nk = K >> 6;
    stage(0, 0);
    if (nk > 1) stage(1, 64);
    for (int t = 0; t < nk; ++t) {
        int cur = t & 1;
        if (t + 1 < nk) {
            asm volatile("s_waitcnt vmcnt(6)" ::: "memory");   // tile t landed
        } else {
            asm volatile("s_waitcnt vmcnt(0)" ::: "memory");
        }
        __builtin_amdgcn_sched_barrier(0);
        __builtin_amdgcn_s_barrier();
        unsigned aB = (unsigned)(size_t)(lds_u16*)&As[cur][0];
        unsigned bB = (unsigned)(size_t)(lds_u16*)&Bs[cur][0];
        #pragma unroll
        for (int ks = 0; ks < 2; ++ks) {
            unsigned soff = (unsigned)((((ks * 4) + l4) ^ l7) * 16);
            bf16x8 av[4], bv[2];
            #pragma unroll
            for (int i = 0; i < 4; ++i) av[i] = ldsr(aB + aoff[i] + soff);
            #pragma unroll
            for (int j = 0; j < 2; ++j) bv[j] = ldsr(bB + boff[j] + soff);
            asm volatile("s_waitcnt lgkmcnt(0)" ::: "memory");
            __builtin_amdgcn_sched_barrier(0);
            __builtin_amdgcn_s_setprio(1);
            #pragma unroll
            for (int i = 0; i < 4; ++i)
                #pragma unroll
                for (int j = 0; j < 2; ++j)
                    acc[i][j] = __builtin_amdgcn_mfma_f32_16x16x32_bf16(av[i], bv[j], acc[i][j], 0, 0, 0);
            __builtin_amdgcn_s_setprio(0);
        }
        asm volatile("s_waitcnt lgkmcnt(0)" ::: "memory");     // reads of buf[cur] done
        __builtin_amdgcn_sched_barrier(0);
        __builtin_amdgcn_s_barrier();
        if (t + 2 < nk) stage(cur, (t + 2) << 6);              // overwrite freed buffer
    }

    if (MODE == 0) {
        float* out = (float*)outv;
        #pragma unroll
        for (int i = 0; i < 4; ++i) {
            int mrow = m0 + wr*64 + i*16 + l4*4;
            #pragma unroll
            for (int j = 0; j < 2; ++j) {
                int e = e0 + wc*32 + j*16 + l15;
                float bval = bias[e];
                #pragma unroll
                for (int r = 0; r < 4; ++r) {
                    int m = mrow + r;
                    if (m >= M) continue;
                    out[(size_t)m * 1024 + e] = acc[i][j][r] + bval + res[(size_t)m * 1024 + e];
                }
            }
        }
    } else {
        unsigned short* out = (unsigned short*)outv;
        #pragma unroll
        for (int i = 0; i < 4; ++i) {
            int mrow = m0 + wr*64 + i*16 + l4*4;
            #pragma unroll
            for (int j = 0; j < 2; ++j) {
                int e = e0 + wc*32 + j*16 + l15;
                float bval = bias[e];
                #pragma unroll
                for (int r = 0; r < 4; ++r) {
                    int m = mrow + r;
                    if (m >= M) continue;
                    float val = acc[i][j][r] + bval;
                    val = 0.5f * val * (1.0f + erff(val * 0.70710678118654752f));
                    out[(size_t)m * FF_ + e] = f2b(val);
                }
            }
        }
    }
}

// ---------------- fp32 tiled GEMM (final 64-col projection only) ----------------
__global__ __launch_bounds__(256)
void gemm_kernel(const float* __restrict__ A, const float* __restrict__ W,
                 const float* __restrict__ bias, float* __restrict__ C,
                 int M, int K, int E) {
    __shared__ float As[32][64];
    __shared__ float Ws[32][64];
    int tid = threadIdx.x;
    int m0 = blockIdx.x * 64, e0 = blockIdx.y * 64;
    int tx = tid & 15, ty = tid >> 4;
    int lrow = tid >> 2;
    int lkc  = (tid & 3) * 8;
    float acc[4][4] = {};
    const float* Arow = A + (size_t)(m0 + lrow) * K + lkc;
    const float* Wrow = W + (size_t)(e0 + lrow) * K + lkc;
    bool aval = (m0 + lrow) < M;

    for (int k0 = 0; k0 < K; k0 += 32) {
        float4 a0 = make_float4(0.f,0.f,0.f,0.f), a1 = a0;
        if (aval) {
            a0 = *(const float4*)(Arow + k0);
            a1 = *(const float4*)(Arow + k0 + 4);
        }
        float4 w0 = *(const float4*)(Wrow + k0);
        float4 w1 = *(const float4*)(Wrow + k0 + 4);
        As[lkc+0][lrow] = a0.x; As[lkc+1][lrow] = a0.y;
        As[lkc+2][lrow] = a0.z; As[lkc+3][lrow] = a0.w;
        As[lkc+4][lrow] = a1.x; As[lkc+5][lrow] = a1.y;
        As[lkc+6][lrow] = a1.z; As[lkc+7][lrow] = a1.w;
        Ws[lkc+0][lrow] = w0.x; Ws[lkc+1][lrow] = w0.y;
        Ws[lkc+2][lrow] = w0.z; Ws[lkc+3][lrow] = w0.w;
        Ws[lkc+4][lrow] = w1.x; Ws[lkc+5][lrow] = w1.y;
        Ws[lkc+6][lrow] = w1.z; Ws[lkc+7][lrow] = w1.w;
        __syncthreads();
        #pragma unroll
        for (int kk = 0; kk < 32; ++kk) {
            float4 a = *(const float4*)(&As[kk][ty*4]);
            float4 ww = *(const float4*)(&Ws[kk][tx*4]);
            acc[0][0] += a.x*ww.x; acc[0][1] += a.x*ww.y; acc[0][2] += a.x*ww.z; acc[0][3] += a.x*ww.w;
            acc[1][0] += a.y*ww.x; acc[1][1] += a.y*ww.y; acc[1][2] += a.y*ww.z; acc[1][3] += a.y*ww.w;
            acc[2][0] += a.z*ww.x; acc[2][1] += a.z*ww.y; acc[2][2] += a.z*ww.z; acc[2][3] += a.z*ww.w;
            acc[3][0] += a.w*ww.x; acc[3][1] += a.w*ww.y; acc[3][2] += a.w*ww.z; acc[3][3] += a.w*ww.w;
        }
        __syncthreads();
    }
    #pragma unroll
    for (int i = 0; i < 4; ++i) {
        int m = m0 + ty*4 + i;
        if (m >= M) continue;
        #pragma unroll
        for (int j = 0; j < 4; ++j) {
            int e = e0 + tx*4 + j;
            C[(size_t)m * E + e] = acc[i][j] + bias[e];
        }
    }
}

// ---------------- V transpose: [s][b][h*64+d] bf16 -> [bh][d][1024] bf16 ----------------
__global__ __launch_bounds__(256)
void vtr_kernel(const unsigned short* __restrict__ vin,
                unsigned short* __restrict__ vout) {
    __shared__ unsigned short T[64][65];
    int tt = blockIdx.x;
    int bh = blockIdx.y;
    int b = bh >> 4, h = bh & 15;
    int tid = threadIdx.x;
    #pragma unroll
    for (int rep = 0; rep < 2; ++rep) {
        int slot = rep * 256 + tid;
        int r = slot >> 3, ch = slot & 7;
        int t = tt * 64 + r;
        unsigned short e[8] = {0,0,0,0,0,0,0,0};
        if (t < S_) {
            const unsigned short* src = vin + ((size_t)t * B_ + b) * D_ + h * HD_ + ch * 8;
            *(ushort4*)&e[0] = *(const ushort4*)(src);
            *(ushort4*)&e[4] = *(const ushort4*)(src + 4);
        }
        #pragma unroll
        for (int u = 0; u < 8; ++u) T[r][ch*8+u] = e[u];
    }
    __syncthreads();
    #pragma unroll
    for (int rep = 0; rep < 2; ++rep) {
        int slot = rep * 256 + tid;
        int d = slot >> 3, ch = slot & 7;
        unsigned short e[8];
        #pragma unroll
        for (int u = 0; u < 8; ++u) e[u] = T[ch*8+u][d];
        unsigned short* dst = vout + ((size_t)bh * 64 + d) * 1024 + tt * 64 + ch * 8;
        *(ushort4*)(dst)     = *(ushort4*)&e[0];
        *(ushort4*)(dst + 4) = *(ushort4*)&e[4];
    }
}

// ---------------- bf16 MFMA flash attention: 64 q x (b,h), KVBLK=128 ----------------
// (round-20 proven) Row sums on the matrix pipe; setprio around MFMA clusters;
// native __bf16 casts for P. LDS 48 KB -> 3 blocks/CU.
__global__ __launch_bounds__(256)
void mattn_kernel(const unsigned short* __restrict__ qg,
                  const unsigned short* __restrict__ kg,
                  const unsigned short* __restrict__ vt,
                  unsigned short* __restrict__ o) {
    __shared__ __align__(16) unsigned short Ks[128 * 64];
    __shared__ __align__(16) unsigned short Vs[64 * 128];
    __shared__ __align__(16) unsigned short Ps[4][16 * 128];

    int bid = blockIdx.x;
    int qt = bid & 15;
    int bh = bid >> 4;
    int b = bh >> 4, h = bh & 15;
    int tid = threadIdx.x;
    int w = tid >> 6, lane = tid & 63;
    int l15 = lane & 15, l4 = lane >> 4, l7 = lane & 7;
    int q0 = qt * 64 + w * 16;

    bf16x8 qfr[2];
    {
        int qr = q0 + l15; if (qr > S_ - 1) qr = S_ - 1;
        const unsigned short* qrow = qg + ((size_t)qr * B_ + b) * D_ + h * HD_;
        qfr[0] = *(const bf16x8*)(qrow + l4 * 8);
        qfr[1] = *(const bf16x8*)(qrow + 32 + l4 * 8);
    }
    bf16x8 onesf;
    #pragma unroll
    for (int z = 0; z < 8; ++z) onesf[z] = (__bf16)1.0f;

    f32x4 accO[4] = {};
    f32x4 accS = {0.f, 0.f, 0.f, 0.f};          // MFMA-computed row sums
    float mreg[4] = {-1e30f, -1e30f, -1e30f, -1e30f};

    for (int t0 = 0; t0 < 1024; t0 += 128) {
        __syncthreads();
        // stage K: 128 rows x 8 chunks (1024 slots, 4/thread)
        #pragma unroll
        for (int rep = 0; rep < 4; ++rep) {
            int slot = rep * 256 + tid;
            int r = slot >> 3, c = slot & 7;
            int tr = t0 + r; if (tr > S_ - 1) tr = S_ - 1;
            gl16(kg + ((size_t)tr * B_ + b) * D_ + h * HD_ + (c ^ (r & 7)) * 8,
                 &Ks[slot * 8]);
        }
        // stage V: 64 d-rows x 16 chunks (1024 slots, 4/thread)
        #pragma unroll
        for (int rep = 0; rep < 4; ++rep) {
            int slot = rep * 256 + tid;
            int r = slot >> 4, c = slot & 15;
            gl16(vt + ((size_t)bh * 64 + r) * 1024 + t0 + (c ^ (r & 7)) * 8,
                 &Vs[slot * 8]);
        }
        __syncthreads();

        // ---- QK^T: s[j] covers t-cols j*16+l15, j=0..7 ----
        f32x4 s[8] = {};
        __builtin_amdgcn_s_setprio(1);
        #pragma unroll
        for (int ks = 0; ks < 2; ++ks) {
            unsigned soff = (unsigned)((((ks * 4) + l4) ^ l7) * 16);
            #pragma unroll
            for (int j = 0; j < 8; ++j) {
                bf16x8 kf = *(const bf16x8*)((const char*)Ks + (j*16 + l15) * 128 + soff);
                s[j] = __builtin_amdgcn_mfma_f32_16x16x32_bf16(qfr[ks], kf, s[j], 0, 0, 0);
            }
        }
        __builtin_amdgcn_s_setprio(0);
        #pragma unroll
        for (int j = 0; j < 8; ++j) {
            int t = t0 + j * 16 + l15;
            if (t >= S_) { s[j][0] = -1e30f; s[j][1] = -1e30f; s[j][2] = -1e30f; s[j][3] = -1e30f; }
        }
        // ---- online softmax: max reduce, exp + P write (sums via MFMA below) ----
        float rm[4], sc[4];
        #pragma unroll
        for (int r = 0; r < 4; ++r) {
            rm[r] = fmaxf(fmaxf(s[0][r], s[1][r]), fmaxf(s[2][r], s[3][r]));
            rm[r] = fmaxf(rm[r], fmaxf(fmaxf(s[4][r], s[5][r]), fmaxf(s[6][r], s[7][r])));
        }
        #pragma unroll
        for (int mk = 1; mk <= 8; mk <<= 1) {
            #pragma unroll
            for (int r = 0; r < 4; ++r) rm[r] = fmaxf(rm[r], __shfl_xor(rm[r], mk));
        }
        #pragma unroll
        for (int r = 0; r < 4; ++r) {
            float mn = fmaxf(mreg[r], rm[r]);
            sc[r] = __expf(mreg[r] - mn);
            mreg[r] = mn;
        }
        #pragma unroll
        for (int j = 0; j < 8; ++j) {
            int inb = (j * 16 + l15) * 2;            // byte col in 256B row
            #pragma unroll
            for (int r = 0; r < 4; ++r) {
                float p = __expf(s[j][r] - mreg[r]);
                int row = l4 * 4 + r;
                *(__bf16*)((char*)&Ps[w][0] + row * 256 +
                    ((((inb >> 4) ^ (row & 7)) << 4)) + (inb & 15)) = (__bf16)p;
            }
        }
        #pragma unroll
        for (int j = 0; j < 4; ++j) {
            accO[j][0] *= sc[0]; accO[j][1] *= sc[1];
            accO[j][2] *= sc[2]; accO[j][3] *= sc[3];
        }
        accS[0] *= sc[0]; accS[1] *= sc[1];
        accS[2] *= sc[2]; accS[3] *= sc[3];
        // ---- PV: A = Ps (16q x 128t), B = Vs (64d x 128t); 4 k-slices ----
        // plus B=ones fragment: accS[q-row] += sum_t P[q][t]
        __builtin_amdgcn_s_setprio(1);
        #pragma unroll
        for (int ks = 0; ks < 4; ++ks) {
            unsigned soff = (unsigned)((((ks * 4) + l4) ^ l7) * 16);
            bf16x8 pf = *(const bf16x8*)((const char*)&Ps[w][0] + l15 * 256 + soff);
            #pragma unroll
            for (int j = 0; j < 4; ++j) {
                bf16x8 vf = *(const bf16x8*)((const char*)Vs + (j*16 + l15) * 256 + soff);
                accO[j] = __builtin_amdgcn_mfma_f32_16x16x32_bf16(pf, vf, accO[j], 0, 0, 0);
            }
            accS = __builtin_amdgcn_mfma_f32_16x16x32_bf16(pf, onesf, accS, 0, 0, 0);
        }
        __builtin_amdgcn_s_setprio(0);
    }
    #pragma unroll
    for (int r = 0; r < 4; ++r) {
        int q = q0 + l4 * 4 + r;
        if (q >= S_) continue;
        float inv = 1.0f / accS[r];
        unsigned short* orow = o + ((size_t)q * B_ + b) * D_ + h * HD_;
        #pragma unroll
        for (int j = 0; j < 4; ++j)
            orow[j * 16 + l15] = f2b(accO[j][r] * inv);
    }
}

extern "C" void kernel_launch(void* const* d_in, const int* in_sizes, int n_in,
                              void* d_out, int out_size, void* d_ws, size_t ws_size,
                              hipStream_t stream) {
    const int*   tokens = (const int*)  d_in[0];
    const float* Wemb   = (const float*)d_in[1];
    const float* Wq     = (const float*)d_in[2];
    const float* bq     = (const float*)d_in[3];
    const float* Wk     = (const float*)d_in[4];
    const float* bk     = (const float*)d_in[5];
    const float* Wv     = (const float*)d_in[6];
    const float* bv     = (const float*)d_in[7];
    const float* Wo     = (const float*)d_in[8];
    const float* bo     = (const float*)d_in[9];
    const float* ln1g   = (const float*)d_in[10];
    const float* ln1b   = (const float*)d_in[11];
    const float* ln2g   = (const float*)d_in[12];
    const float* ln2b   = (const float*)d_in[13];
    const float* W1     = (const float*)d_in[14];
    const float* b1     = (const float*)d_in[15];
    const float* W2     = (const float*)d_in[16];
    const float* b2     = (const float*)d_in[17];
    const float* Wout   = (const float*)d_in[18];
    const float* bout   = (const float*)d_in[19];
    float* out = (float*)d_out;

    const size_t ND = (size_t)N_ * D_;
    const size_t NF = (size_t)N_ * FF_;
    const size_t M1 = (size_t)D_ * D_;
    const size_t M4 = (size_t)FF_ * D_;
    const size_t VT = (size_t)64 * 64 * 1024;

    float* x  = (float*)d_ws;
    unsigned short* hb = (unsigned short*)(x + ND);
    unsigned short* qb = hb + ND;
    unsigned short* kb = qb + ND;
    unsigned short* vb = kb + ND;
    unsigned short* ob = vb + ND;
    unsigned short* vt = ob + ND;
    unsigned short* f1 = vt + VT;
    unsigned short* wb = f1 + NF;           // 12M bf16 per-layer weights

    dim3 blk(256);
    embed_kernel<<<N_, blk, 0, stream>>>(tokens, Wemb, x);

    dim3 gQKV(16, 48);   // 256x64 tiles: M=4000->16, E=3072->48 (768 blocks)
    dim3 gW1(32, 64);    // 128x64 tiles: E=4096->64 (2048 blocks)
    dim3 gE64(32, 16);   // 128x64 tiles, E=1024->16 (512 blocks)
    dim3 gCv(12288);
    dim3 gVt(16, 64);
    dim3 gAt(16 * 64);   // 16 q-tiles of 64 x 64 (b,h)
    dim3 gOut((N_ + 63) / 64, 1);

    for (int l = 0; l < L_; ++l) {
        cvtw_kernel<<<gCv, blk, 0, stream>>>(Wq + l*M1, Wk + l*M1, Wv + l*M1,
                                             Wo + l*M1, W1 + l*M4, W2 + l*M4, wb);
        ln_kernel<<<N_, blk, 0, stream>>>(x, ln1g + l*D_, ln1b + l*D_, hb);
        ggemm_kernel<<<gQKV, dim3(512), 0, stream>>>(hb, wb,
            bq + l*D_, bk + l*D_, bv + l*D_, qb, kb, vb, N_, D_);
        vtr_kernel<<<gVt, blk, 0, stream>>>(vb, vt);
        mattn_kernel<<<gAt, blk, 0, stream>>>(qb, kb, vt, ob);
        dgemm_kernel<0><<<gE64, blk, 0, stream>>>(ob, wb + 3*M1,
            bo + l*D_, x, x, N_, D_);
        ln_kernel<<<N_, blk, 0, stream>>>(x, ln2g + l*D_, ln2b + l*D_, hb);
        dgemm_kernel<1><<<gW1, blk, 0, stream>>>(hb, wb + 4*M1,
            b1 + l*FF_, nullptr, f1, N_, D_);
        dgemm_kernel<0><<<gE64, blk, 0, stream>>>(f1, wb + 4*M1 + M4,
            b2 + l*D_, x, x, N_, FF_);
    }
    gemm_kernel<<<gOut, blk, 0, stream>>>(x, Wout, bout, out, N_, D_, 64);
}

// Round 22
// 1058.777 us; speedup vs baseline: 1.0614x; 1.0034x over previous
//
#include <hip/hip_runtime.h>
#include <hip/hip_bf16.h>
#include <math.h>

#define S_   1000
#define B_   4
#define D_   1024
#define H_   16
#define HD_  64
#define L_   4
#define FF_  4096
#define N_   (S_*B_)   /* 4000 token rows */

typedef __bf16 bf16x8 __attribute__((ext_vector_type(8)));
typedef float  f32x4  __attribute__((ext_vector_type(4)));
typedef __attribute__((address_space(3))) unsigned short lds_u16;

__device__ __forceinline__ unsigned short f2b(float f) {
    unsigned u = __builtin_bit_cast(unsigned, f);
    u = (u + 0x7FFFu + ((u >> 16) & 1u)) >> 16;   // RNE
    return (unsigned short)u;
}
__device__ __forceinline__ float b2f(unsigned short s) {
    unsigned u = (unsigned)s << 16;
    return __builtin_bit_cast(float, u);
}

__device__ __forceinline__ void gl16(const void* g, void* l) {
    __builtin_amdgcn_global_load_lds(
        (const __attribute__((address_space(1))) unsigned int*)g,
        (__attribute__((address_space(3))) unsigned int*)l, 16, 0, 0);
}

// inline-asm LDS read: invisible to compiler's mem-dep model, so it cannot
// auto-insert vmcnt(0) between global_load_lds and this read.
__device__ __forceinline__ bf16x8 ldsr(unsigned addr) {
    bf16x8 r;
    asm volatile("ds_read_b128 %0, %1" : "=v"(r) : "v"(addr));
    return r;
}

// ---------------- embedding lookup ----------------
__global__ void embed_kernel(const int* __restrict__ tokens,
                             const float* __restrict__ emb,
                             float* __restrict__ x) {
    int n = blockIdx.x;
    int tok = tokens[n];
    const float4* src = (const float4*)(emb + (size_t)tok * D_);
    float4* dst = (float4*)(x + (size_t)n * D_);
    dst[threadIdx.x] = src[threadIdx.x];
}

// ---------------- weight fp32->bf16 conversion (one layer, 12M elems) ----------------
__global__ __launch_bounds__(256)
void cvtw_kernel(const float* __restrict__ wq, const float* __restrict__ wk,
                 const float* __restrict__ wv, const float* __restrict__ wo,
                 const float* __restrict__ w1, const float* __restrict__ w2,
                 unsigned short* __restrict__ dst) {
    const size_t M1 = (size_t)D_ * D_;
    const size_t M4 = (size_t)FF_ * D_;
    size_t i = ((size_t)blockIdx.x * 256 + threadIdx.x) * 4;
    const float* src; size_t off;
    if      (i < M1)        { src = wq; off = i; }
    else if (i < 2*M1)      { src = wk; off = i - M1; }
    else if (i < 3*M1)      { src = wv; off = i - 2*M1; }
    else if (i < 4*M1)      { src = wo; off = i - 3*M1; }
    else if (i < 4*M1+M4)   { src = w1; off = i - 4*M1; }
    else                    { src = w2; off = i - 4*M1 - M4; }
    float4 v = *(const float4*)(src + off);
    ushort4 u;
    u.x = f2b(v.x); u.y = f2b(v.y); u.z = f2b(v.z); u.w = f2b(v.w);
    *(ushort4*)(dst + i) = u;
}

// ---------------- layernorm: fp32 in, bf16 out ----------------
__global__ __launch_bounds__(256)
void ln_kernel(const float* __restrict__ in,
               const float* __restrict__ g,
               const float* __restrict__ b,
               unsigned short* __restrict__ out) {
    int n = blockIdx.x;
    int tid = threadIdx.x;
    const float4* row = (const float4*)(in + (size_t)n * D_);
    float4 v = row[tid];
    float s  = v.x + v.y + v.z + v.w;
    float sq = v.x*v.x + v.y*v.y + v.z*v.z + v.w*v.w;
    #pragma unroll
    for (int off = 32; off; off >>= 1) {
        s  += __shfl_down(s, off);
        sq += __shfl_down(sq, off);
    }
    __shared__ float rs[4], rq[4];
    int wid = tid >> 6;
    if ((tid & 63) == 0) { rs[wid] = s; rq[wid] = sq; }
    __syncthreads();
    s  = rs[0] + rs[1] + rs[2] + rs[3];
    sq = rq[0] + rq[1] + rq[2] + rq[3];
    float mean = s * (1.0f / D_);
    float var  = sq * (1.0f / D_) - mean * mean;
    float rstd = rsqrtf(var + 1e-5f);
    float4 gg = ((const float4*)g)[tid];
    float4 bb = ((const float4*)b)[tid];
    ushort4 o;
    o.x = f2b((v.x - mean) * rstd * gg.x + bb.x);
    o.y = f2b((v.y - mean) * rstd * gg.y + bb.y);
    o.z = f2b((v.z - mean) * rstd * gg.z + bb.z);
    o.w = f2b((v.w - mean) * rstd * gg.w + bb.w);
    ((ushort4*)(out + (size_t)n * D_))[tid] = o;
}

// ---------------- 256x64 tail-staged GEMM, counted-lgkm overlap ----------------
// QKV split + fused RoPE. All 12 ds_reads (both ks phases) issued up front;
// lgkmcnt(6) -> ks0 MFMAs (ks1 reads fly underneath) -> lgkmcnt(0) -> ks1.
__global__ __launch_bounds__(512, 4)
void ggemm_kernel(const unsigned short* __restrict__ A,
                  const unsigned short* __restrict__ W,
                  const float* __restrict__ bb0, const float* __restrict__ bb1,
                  const float* __restrict__ bb2,
                  unsigned short* __restrict__ o0, unsigned short* __restrict__ o1,
                  unsigned short* __restrict__ o2,
                  int M, int K) {
    __shared__ __align__(16) unsigned short As[2][256 * 64];   // 64 KB
    __shared__ __align__(16) unsigned short Bs[2][64 * 64];    // 16 KB
    int tid = threadIdx.x;
    int w = tid >> 6, lane = tid & 63;
    int m0 = blockIdx.x * 256, e0 = blockIdx.y * 64;
    int l15 = lane & 15, l4 = lane >> 4, l7 = lane & 7;

    f32x4 acc[2][4] = {};

    auto stage = [&](int buf, int kt) {
        #pragma unroll
        for (int rep = 0; rep < 4; ++rep) {
            int slot = rep * 512 + tid;            // A: 256 rows x 8 chunks
            int r = slot >> 3, c = slot & 7;
            int ar = m0 + r; if (ar > M - 1) ar = M - 1;
            gl16(A + (size_t)ar * K + kt + (c ^ (r & 7)) * 8, &As[buf][slot * 8]);
        }
        {
            int slot = tid;                        // B: 64 rows x 8 chunks
            int r = slot >> 3, c = slot & 7;
            gl16(W + (size_t)(e0 + r) * K + kt + (c ^ (r & 7)) * 8, &Bs[buf][slot * 8]);
        }
    };

    int aoff[2], boff[4];
    #pragma unroll
    for (int i = 0; i < 2; ++i) aoff[i] = (w * 32 + i * 16 + l15) * 128;
    #pragma unroll
    for (int j = 0; j < 4; ++j) boff[j] = (j * 16 + l15) * 128;

    unsigned s0 = (unsigned)(((0 + l4) ^ l7) * 16);
    unsigned s1 = (unsigned)(((4 + l4) ^ l7) * 16);

    int nk = K >> 6;
    stage(0, 0);
    if (nk > 1) stage(1, 64);
    for (int t = 0; t < nk; ++t) {
        int cur = t & 1;
        if (t + 1 < nk) {
            asm volatile("s_waitcnt vmcnt(5)" ::: "memory");   // tile t landed
        } else {
            asm volatile("s_waitcnt vmcnt(0)" ::: "memory");
        }
        __builtin_amdgcn_sched_barrier(0);
        __builtin_amdgcn_s_barrier();
        unsigned aB = (unsigned)(size_t)(lds_u16*)&As[cur][0];
        unsigned bB = (unsigned)(size_t)(lds_u16*)&Bs[cur][0];
        // issue ALL 12 reads: ks0 (6) then ks1 (6); DS reads retire in order
        bf16x8 av0[2], bv0[4], av1[2], bv1[4];
        #pragma unroll
        for (int i = 0; i < 2; ++i) av0[i] = ldsr(aB + aoff[i] + s0);
        #pragma unroll
        for (int j = 0; j < 4; ++j) bv0[j] = ldsr(bB + boff[j] + s0);
        #pragma unroll
        for (int i = 0; i < 2; ++i) av1[i] = ldsr(aB + aoff[i] + s1);
        #pragma unroll
        for (int j = 0; j < 4; ++j) bv1[j] = ldsr(bB + boff[j] + s1);
        asm volatile("s_waitcnt lgkmcnt(6)" ::: "memory");     // ks0 frags landed
        __builtin_amdgcn_sched_barrier(0);
        __builtin_amdgcn_s_setprio(1);
        #pragma unroll
        for (int i = 0; i < 2; ++i)
            #pragma unroll
            for (int j = 0; j < 4; ++j)
                acc[i][j] = __builtin_amdgcn_mfma_f32_16x16x32_bf16(av0[i], bv0[j], acc[i][j], 0, 0, 0);
        __builtin_amdgcn_s_setprio(0);
        asm volatile("s_waitcnt lgkmcnt(0)" ::: "memory");     // ks1 frags landed
        __builtin_amdgcn_sched_barrier(0);
        __builtin_amdgcn_s_setprio(1);
        #pragma unroll
        for (int i = 0; i < 2; ++i)
            #pragma unroll
            for (int j = 0; j < 4; ++j)
                acc[i][j] = __builtin_amdgcn_mfma_f32_16x16x32_bf16(av1[i], bv1[j], acc[i][j], 0, 0, 0);
        __builtin_amdgcn_s_setprio(0);
        __builtin_amdgcn_sched_barrier(0);
        __builtin_amdgcn_s_barrier();                          // all reads drained above
        if (t + 2 < nk) stage(cur, (t + 2) << 6);              // overwrite freed buffer
    }

    // ---- epilogue (C/D: col=lane&15, row=(lane>>4)*4+reg) ----
    int sel = e0 >> 10;                     // 64-tile never crosses 1024 boundary
    int eobase = e0 & 1023;
    const float* bp = (sel == 0) ? bb0 : (sel == 1) ? bb1 : bb2;
    unsigned short* op = (sel == 0) ? o0 : (sel == 1) ? o1 : o2;
    if (sel == 2) {
        #pragma unroll
        for (int i = 0; i < 2; ++i) {
            int mrow = m0 + w*32 + i*16 + l4*4;
            #pragma unroll
            for (int j = 0; j < 4; ++j) {
                int eo = eobase + j*16 + l15;
                float bval = bp[eo];
                #pragma unroll
                for (int r = 0; r < 4; ++r) {
                    int m = mrow + r;
                    if (m >= M) continue;
                    op[(size_t)m * 1024 + eo] = f2b(acc[i][j][r] + bval);
                }
            }
        }
    } else {
        // fused RoPE: pair (d, d+32) = acc[i][jj], acc[i][jj+2]; rotate on fp32
        float scale = (sel == 0) ? 0.125f : 1.0f;
        #pragma unroll
        for (int i = 0; i < 2; ++i) {
            int mrow = m0 + w*32 + i*16 + l4*4;
            #pragma unroll
            for (int jj = 0; jj < 2; ++jj) {
                int d5 = jj*16 + l15;                 // 0..31 within head
                int eo_a = eobase + d5;
                int eo_b = eo_a + 32;
                float ba = bp[eo_a], bbv = bp[eo_b];
                float invf = __expf(-(float)d5 * 0.2878231366242557f); // ln(1e4)/32
                #pragma unroll
                for (int r = 0; r < 4; ++r) {
                    int m = mrow + r;
                    if (m >= M) continue;
                    int s = m >> 2;                   // n = s*B + b, B=4
                    float ang = (float)s * invf;
                    float sn, cs;
                    __sincosf(ang, &sn, &cs);
                    float a = acc[i][jj][r]   + ba;
                    float c = acc[i][jj+2][r] + bbv;
                    op[(size_t)m * 1024 + eo_a] = f2b((a*cs - c*sn) * scale);
                    op[(size_t)m * 1024 + eo_b] = f2b((c*cs + a*sn) * scale);
                }
            }
        }
    }
}

// ---------------- 128x64 tail-staged GEMM, counted-lgkm overlap ----------------
// 4 waves 2x2, wave tile 64x32, 48 KB LDS -> 3 blocks/CU.
// MODE 0: +residual — out fp32 stride 1024
// MODE 1: GELU — out bf16 stride FF_
template<int MODE>
__global__ __launch_bounds__(256, 2)
void dgemm_kernel(const unsigned short* __restrict__ A,
                  const unsigned short* __restrict__ W,
                  const float* __restrict__ bias,
                  const float* __restrict__ res,
                  void* __restrict__ outv,
                  int M, int K) {
    __shared__ __align__(16) unsigned short As[2][128 * 64];   // 32 KB
    __shared__ __align__(16) unsigned short Bs[2][64 * 64];    // 16 KB
    int tid = threadIdx.x;
    int w = tid >> 6, lane = tid & 63;
    int wr = w >> 1, wc = w & 1;
    int m0 = blockIdx.x * 128, e0 = blockIdx.y * 64;
    int l15 = lane & 15, l4 = lane >> 4, l7 = lane & 7;

    f32x4 acc[4][2] = {};

    auto stage = [&](int buf, int kt) {
        #pragma unroll
        for (int rep = 0; rep < 4; ++rep) {
            int slot = rep * 256 + tid;            // A: 128 rows
            int r = slot >> 3, c = slot & 7;
            int ar = m0 + r; if (ar > M - 1) ar = M - 1;
            gl16(A + (size_t)ar * K + kt + (c ^ (r & 7)) * 8, &As[buf][slot * 8]);
        }
        #pragma unroll
        for (int rep = 0; rep < 2; ++rep) {
            int slot = rep * 256 + tid;            // B: 64 rows
            int r = slot >> 3, c = slot & 7;
            gl16(W + (size_t)(e0 + r) * K + kt + (c ^ (r & 7)) * 8, &Bs[buf][slot * 8]);
        }
    };

    int aoff[4], boff[2];
    #pragma unroll
    for (int i = 0; i < 4; ++i) aoff[i] = (wr * 64 + i * 16 + l15) * 128;
    #pragma unroll
    for (int j = 0; j < 2; ++j) boff[j] = (wc * 32 + j * 16 + l15) * 128;

    unsigned s0 = (unsigned)(((0 + l4) ^ l7) * 16);
    unsigned s1 = (unsigned)(((4 + l4) ^ l7) * 16);

    int nk = K >> 6;
    stage(0, 0);
    if (nk > 1) stage(1, 64);
    for (int t = 0; t < nk; ++t) {
        int cur = t & 1;
        if (t + 1 < nk) {
            asm volatile("s_waitcnt vmcnt(6)" ::: "memory");   // tile t landed
        } else {
            asm volatile("s_waitcnt vmcnt(0)" ::: "memory");
        }
        __builtin_amdgcn_sched_barrier(0);
        __builtin_amdgcn_s_barrier();
        unsigned aB = (unsigned)(size_t)(lds_u16*)&As[cur][0];
        unsigned bB = (unsigned)(size_t)(lds_u16*)&Bs[cur][0];
        // issue ALL 12 reads: ks0 (6) then ks1 (6); DS reads retire in order
        bf16x8 av0[4], bv0[2], av1[4], bv1[2];
        #pragma unroll
        for (int i = 0; i < 4; ++i) av0[i] = ldsr(aB + aoff[i] + s0);
        #pragma unroll
        for (int j = 0; j < 2; ++j) bv0[j] = ldsr(bB + boff[j] + s0);
        #pragma unroll
        for (int i = 0; i < 4; ++i) av1[i] = ldsr(aB + aoff[i] + s1);
        #pragma unroll
        for (int j = 0; j < 2; ++j) bv1[j] = ldsr(bB + boff[j] + s1);
        asm volatile("s_waitcnt lgkmcnt(6)" ::: "memory");     // ks0 frags landed
        __builtin_amdgcn_sched_barrier(0);
        __builtin_amdgcn_s_setprio(1);
        #pragma unroll
        for (int i = 0; i < 4; ++i)
            #pragma unroll
            for (int j = 0; j < 2; ++j)
                acc[i][j] = __builtin_amdgcn_mfma_f32_16x16x32_bf16(av0[i], bv0[j], acc[i][j], 0, 0, 0);
        __builtin_amdgcn_s_setprio(0);
        asm volatile("s_waitcnt lgkmcnt(0)" ::: "memory");     // ks1 frags landed
        __builtin_amdgcn_sched_barrier(0);
        __builtin_amdgcn_s_setprio(1);
        #pragma unroll
        for (int i = 0; i < 4; ++i)
            #pragma unroll
            for (int j = 0; j < 2; ++j)
                acc[i][j] = __builtin_amdgcn_mfma_f32_16x16x32_bf16(av1[i], bv1[j], acc[i][j], 0, 0, 0);
        __builtin_amdgcn_s_setprio(0);
        __builtin_amdgcn_sched_barrier(0);
        __builtin_amdgcn_s_barrier();                          // all reads drained above
        if (t + 2 < nk) stage(cur, (t + 2) << 6);              // overwrite freed buffer
    }

    if (MODE == 0) {
        float* out = (float*)outv;
        #pragma unroll
        for (int i = 0; i < 4; ++i) {
            int mrow = m0 + wr*64 + i*16 + l4*4;
            #pragma unroll
            for (int j = 0; j < 2; ++j) {
                int e = e0 + wc*32 + j*16 + l15;
                float bval = bias[e];
                #pragma unroll
                for (int r = 0; r < 4; ++r) {
                    int m = mrow + r;
                    if (m >= M) continue;
                    out[(size_t)m * 1024 + e] = acc[i][j][r] + bval + res[(size_t)m * 1024 + e];
                }
            }
        }
    } else {
        unsigned short* out = (unsigned short*)outv;
        #pragma unroll
        for (int i = 0; i < 4; ++i) {
            int mrow = m0 + wr*64 + i*16 + l4*4;
            #pragma unroll
            for (int j = 0; j < 2; ++j) {
                int e = e0 + wc*32 + j*16 + l15;
                float bval = bias[e];
                #pragma unroll
                for (int r = 0; r < 4; ++r) {
                    int m = mrow + r;
                    if (m >= M) continue;
                    float val = acc[i][j][r] + bval;
                    val = 0.5f * val * (1.0f + erff(val * 0.70710678118654752f));
                    out[(size_t)m * FF_ + e] = f2b(val);
                }
            }
        }
    }
}

// ---------------- fp32 tiled GEMM (final 64-col projection only) ----------------
__global__ __launch_bounds__(256)
void gemm_kernel(const float* __restrict__ A, const float* __restrict__ W,
                 const float* __restrict__ bias, float* __restrict__ C,
                 int M, int K, int E) {
    __shared__ float As[32][64];
    __shared__ float Ws[32][64];
    int tid = threadIdx.x;
    int m0 = blockIdx.x * 64, e0 = blockIdx.y * 64;
    int tx = tid & 15, ty = tid >> 4;
    int lrow = tid >> 2;
    int lkc  = (tid & 3) * 8;
    float acc[4][4] = {};
    const float* Arow = A + (size_t)(m0 + lrow) * K + lkc;
    const float* Wrow = W + (size_t)(e0 + lrow) * K + lkc;
    bool aval = (m0 + lrow) < M;

    for (int k0 = 0; k0 < K; k0 += 32) {
        float4 a0 = make_float4(0.f,0.f,0.f,0.f), a1 = a0;
        if (aval) {
            a0 = *(const float4*)(Arow + k0);
            a1 = *(const float4*)(Arow + k0 + 4);
        }
        float4 w0 = *(const float4*)(Wrow + k0);
        float4 w1 = *(const float4*)(Wrow + k0 + 4);
        As[lkc+0][lrow] = a0.x; As[lkc+1][lrow] = a0.y;
        As[lkc+2][lrow] = a0.z; As[lkc+3][lrow] = a0.w;
        As[lkc+4][lrow] = a1.x; As[lkc+5][lrow] = a1.y;
        As[lkc+6][lrow] = a1.z; As[lkc+7][lrow] = a1.w;
        Ws[lkc+0][lrow] = w0.x; Ws[lkc+1][lrow] = w0.y;
        Ws[lkc+2][lrow] = w0.z; Ws[lkc+3][lrow] = w0.w;
        Ws[lkc+4][lrow] = w1.x; Ws[lkc+5][lrow] = w1.y;
        Ws[lkc+6][lrow] = w1.z; Ws[lkc+7][lrow] = w1.w;
        __syncthreads();
        #pragma unroll
        for (int kk = 0; kk < 32; ++kk) {
            float4 a = *(const float4*)(&As[kk][ty*4]);
            float4 ww = *(const float4*)(&Ws[kk][tx*4]);
            acc[0][0] += a.x*ww.x; acc[0][1] += a.x*ww.y; acc[0][2] += a.x*ww.z; acc[0][3] += a.x*ww.w;
            acc[1][0] += a.y*ww.x; acc[1][1] += a.y*ww.y; acc[1][2] += a.y*ww.z; acc[1][3] += a.y*ww.w;
            acc[2][0] += a.z*ww.x; acc[2][1] += a.z*ww.y; acc[2][2] += a.z*ww.z; acc[2][3] += a.z*ww.w;
            acc[3][0] += a.w*ww.x; acc[3][1] += a.w*ww.y; acc[3][2] += a.w*ww.z; acc[3][3] += a.w*ww.w;
        }
        __syncthreads();
    }
    #pragma unroll
    for (int i = 0; i < 4; ++i) {
        int m = m0 + ty*4 + i;
        if (m >= M) continue;
        #pragma unroll
        for (int j = 0; j < 4; ++j) {
            int e = e0 + tx*4 + j;
            C[(size_t)m * E + e] = acc[i][j] + bias[e];
        }
    }
}

// ---------------- V transpose: [s][b][h*64+d] bf16 -> [bh][d][1024] bf16 ----------------
__global__ __launch_bounds__(256)
void vtr_kernel(const unsigned short* __restrict__ vin,
                unsigned short* __restrict__ vout) {
    __shared__ unsigned short T[64][65];
    int tt = blockIdx.x;
    int bh = blockIdx.y;
    int b = bh >> 4, h = bh & 15;
    int tid = threadIdx.x;
    #pragma unroll
    for (int rep = 0; rep < 2; ++rep) {
        int slot = rep * 256 + tid;
        int r = slot >> 3, ch = slot & 7;
        int t = tt * 64 + r;
        unsigned short e[8] = {0,0,0,0,0,0,0,0};
        if (t < S_) {
            const unsigned short* src = vin + ((size_t)t * B_ + b) * D_ + h * HD_ + ch * 8;
            *(ushort4*)&e[0] = *(const ushort4*)(src);
            *(ushort4*)&e[4] = *(const ushort4*)(src + 4);
        }
        #pragma unroll
        for (int u = 0; u < 8; ++u) T[r][ch*8+u] = e[u];
    }
    __syncthreads();
    #pragma unroll
    for (int rep = 0; rep < 2; ++rep) {
        int slot = rep * 256 + tid;
        int d = slot >> 3, ch = slot & 7;
        unsigned short e[8];
        #pragma unroll
        for (int u = 0; u < 8; ++u) e[u] = T[ch*8+u][d];
        unsigned short* dst = vout + ((size_t)bh * 64 + d) * 1024 + tt * 64 + ch * 8;
        *(ushort4*)(dst)     = *(ushort4*)&e[0];
        *(ushort4*)(dst + 4) = *(ushort4*)&e[4];
    }
}

// ---------------- bf16 MFMA flash attention: 64 q x (b,h), KVBLK=128 ----------------
// (round-20 proven) Row sums on the matrix pipe; setprio around MFMA clusters;
// native __bf16 casts for P. LDS 48 KB -> 3 blocks/CU.
__global__ __launch_bounds__(256)
void mattn_kernel(const unsigned short* __restrict__ qg,
                  const unsigned short* __restrict__ kg,
                  const unsigned short* __restrict__ vt,
                  unsigned short* __restrict__ o) {
    __shared__ __align__(16) unsigned short Ks[128 * 64];
    __shared__ __align__(16) unsigned short Vs[64 * 128];
    __shared__ __align__(16) unsigned short Ps[4][16 * 128];

    int bid = blockIdx.x;
    int qt = bid & 15;
    int bh = bid >> 4;
    int b = bh >> 4, h = bh & 15;
    int tid = threadIdx.x;
    int w = tid >> 6, lane = tid & 63;
    int l15 = lane & 15, l4 = lane >> 4, l7 = lane & 7;
    int q0 = qt * 64 + w * 16;

    bf16x8 qfr[2];
    {
        int qr = q0 + l15; if (qr > S_ - 1) qr = S_ - 1;
        const unsigned short* qrow = qg + ((size_t)qr * B_ + b) * D_ + h * HD_;
        qfr[0] = *(const bf16x8*)(qrow + l4 * 8);
        qfr[1] = *(const bf16x8*)(qrow + 32 + l4 * 8);
    }
    bf16x8 onesf;
    #pragma unroll
    for (int z = 0; z < 8; ++z) onesf[z] = (__bf16)1.0f;

    f32x4 accO[4] = {};
    f32x4 accS = {0.f, 0.f, 0.f, 0.f};          // MFMA-computed row sums
    float mreg[4] = {-1e30f, -1e30f, -1e30f, -1e30f};

    for (int t0 = 0; t0 < 1024; t0 += 128) {
        __syncthreads();
        // stage K: 128 rows x 8 chunks (1024 slots, 4/thread)
        #pragma unroll
        for (int rep = 0; rep < 4; ++rep) {
            int slot = rep * 256 + tid;
            int r = slot >> 3, c = slot & 7;
            int tr = t0 + r; if (tr > S_ - 1) tr = S_ - 1;
            gl16(kg + ((size_t)tr * B_ + b) * D_ + h * HD_ + (c ^ (r & 7)) * 8,
                 &Ks[slot * 8]);
        }
        // stage V: 64 d-rows x 16 chunks (1024 slots, 4/thread)
        #pragma unroll
        for (int rep = 0; rep < 4; ++rep) {
            int slot = rep * 256 + tid;
            int r = slot >> 4, c = slot & 15;
            gl16(vt + ((size_t)bh * 64 + r) * 1024 + t0 + (c ^ (r & 7)) * 8,
                 &Vs[slot * 8]);
        }
        __syncthreads();

        // ---- QK^T: s[j] covers t-cols j*16+l15, j=0..7 ----
        f32x4 s[8] = {};
        __builtin_amdgcn_s_setprio(1);
        #pragma unroll
        for (int ks = 0; ks < 2; ++ks) {
            unsigned soff = (unsigned)((((ks * 4) + l4) ^ l7) * 16);
            #pragma unroll
            for (int j = 0; j < 8; ++j) {
                bf16x8 kf = *(const bf16x8*)((const char*)Ks + (j*16 + l15) * 128 + soff);
                s[j] = __builtin_amdgcn_mfma_f32_16x16x32_bf16(qfr[ks], kf, s[j], 0, 0, 0);
            }
        }
        __builtin_amdgcn_s_setprio(0);
        #pragma unroll
        for (int j = 0; j < 8; ++j) {
            int t = t0 + j * 16 + l15;
            if (t >= S_) { s[j][0] = -1e30f; s[j][1] = -1e30f; s[j][2] = -1e30f; s[j][3] = -1e30f; }
        }
        // ---- online softmax: max reduce, exp + P write (sums via MFMA below) ----
        float rm[4], sc[4];
        #pragma unroll
        for (int r = 0; r < 4; ++r) {
            rm[r] = fmaxf(fmaxf(s[0][r], s[1][r]), fmaxf(s[2][r], s[3][r]));
            rm[r] = fmaxf(rm[r], fmaxf(fmaxf(s[4][r], s[5][r]), fmaxf(s[6][r], s[7][r])));
        }
        #pragma unroll
        for (int mk = 1; mk <= 8; mk <<= 1) {
            #pragma unroll
            for (int r = 0; r < 4; ++r) rm[r] = fmaxf(rm[r], __shfl_xor(rm[r], mk));
        }
        #pragma unroll
        for (int r = 0; r < 4; ++r) {
            float mn = fmaxf(mreg[r], rm[r]);
            sc[r] = __expf(mreg[r] - mn);
            mreg[r] = mn;
        }
        #pragma unroll
        for (int j = 0; j < 8; ++j) {
            int inb = (j * 16 + l15) * 2;            // byte col in 256B row
            #pragma unroll
            for (int r = 0; r < 4; ++r) {
                float p = __expf(s[j][r] - mreg[r]);
                int row = l4 * 4 + r;
                *(__bf16*)((char*)&Ps[w][0] + row * 256 +
                    ((((inb >> 4) ^ (row & 7)) << 4)) + (inb & 15)) = (__bf16)p;
            }
        }
        #pragma unroll
        for (int j = 0; j < 4; ++j) {
            accO[j][0] *= sc[0]; accO[j][1] *= sc[1];
            accO[j][2] *= sc[2]; accO[j][3] *= sc[3];
        }
        accS[0] *= sc[0]; accS[1] *= sc[1];
        accS[2] *= sc[2]; accS[3] *= sc[3];
        // ---- PV: A = Ps (16q x 128t), B = Vs (64d x 128t); 4 k-slices ----
        // plus B=ones fragment: accS[q-row] += sum_t P[q][t]
        __builtin_amdgcn_s_setprio(1);
        #pragma unroll
        for (int ks = 0; ks < 4; ++ks) {
            unsigned soff = (unsigned)((((ks * 4) + l4) ^ l7) * 16);
            bf16x8 pf = *(const bf16x8*)((const char*)&Ps[w][0] + l15 * 256 + soff);
            #pragma unroll
            for (int j = 0; j < 4; ++j) {
                bf16x8 vf = *(const bf16x8*)((const char*)Vs + (j*16 + l15) * 256 + soff);
                accO[j] = __builtin_amdgcn_mfma_f32_16x16x32_bf16(pf, vf, accO[j], 0, 0, 0);
            }
            accS = __builtin_amdgcn_mfma_f32_16x16x32_bf16(pf, onesf, accS, 0, 0, 0);
        }
        __builtin_amdgcn_s_setprio(0);
    }
    #pragma unroll
    for (int r = 0; r < 4; ++r) {
        int q = q0 + l4 * 4 + r;
        if (q >= S_) continue;
        float inv = 1.0f / accS[r];
        unsigned short* orow = o + ((size_t)q * B_ + b) * D_ + h * HD_;
        #pragma unroll
        for (int j = 0; j < 4; ++j)
            orow[j * 16 + l15] = f2b(accO[j][r] * inv);
    }
}

extern "C" void kernel_launch(void* const* d_in, const int* in_sizes, int n_in,
                              void* d_out, int out_size, void* d_ws, size_t ws_size,
                              hipStream_t stream) {
    const int*   tokens = (const int*)  d_in[0];
    const float* Wemb   = (const float*)d_in[1];
    const float* Wq     = (const float*)d_in[2];
    const float* bq     = (const float*)d_in[3];
    const float* Wk     = (const float*)d_in[4];
    const float* bk     = (const float*)d_in[5];
    const float* Wv     = (const float*)d_in[6];
    const float* bv     = (const float*)d_in[7];
    const float* Wo     = (const float*)d_in[8];
    const float* bo     = (const float*)d_in[9];
    const float* ln1g   = (const float*)d_in[10];
    const float* ln1b   = (const float*)d_in[11];
    const float* ln2g   = (const float*)d_in[12];
    const float* ln2b   = (const float*)d_in[13];
    const float* W1     = (const float*)d_in[14];
    const float* b1     = (const float*)d_in[15];
    const float* W2     = (const float*)d_in[16];
    const float* b2     = (const float*)d_in[17];
    const float* Wout   = (const float*)d_in[18];
    const float* bout   = (const float*)d_in[19];
    float* out = (float*)d_out;

    const size_t ND = (size_t)N_ * D_;
    const size_t NF = (size_t)N_ * FF_;
    const size_t M1 = (size_t)D_ * D_;
    const size_t M4 = (size_t)FF_ * D_;
    const size_t VT = (size_t)64 * 64 * 1024;

    float* x  = (float*)d_ws;
    unsigned short* hb = (unsigned short*)(x + ND);
    unsigned short* qb = hb + ND;
    unsigned short* kb = qb + ND;
    unsigned short* vb = kb + ND;
    unsigned short* ob = vb + ND;
    unsigned short* vt = ob + ND;
    unsigned short* f1 = vt + VT;
    unsigned short* wb = f1 + NF;           // 12M bf16 per-layer weights

    dim3 blk(256);
    embed_kernel<<<N_, blk, 0, stream>>>(tokens, Wemb, x);

    dim3 gQKV(16, 48);   // 256x64 tiles: M=4000->16, E=3072->48 (768 blocks)
    dim3 gW1(32, 64);    // 128x64 tiles: E=4096->64 (2048 blocks)
    dim3 gE64(32, 16);   // 128x64 tiles, E=1024->16 (512 blocks)
    dim3 gCv(12288);
    dim3 gVt(16, 64);
    dim3 gAt(16 * 64);   // 16 q-tiles of 64 x 64 (b,h)
    dim3 gOut((N_ + 63) / 64, 1);

    for (int l = 0; l < L_; ++l) {
        cvtw_kernel<<<gCv, blk, 0, stream>>>(Wq + l*M1, Wk + l*M1, Wv + l*M1,
                                             Wo + l*M1, W1 + l*M4, W2 + l*M4, wb);
        ln_kernel<<<N_, blk, 0, stream>>>(x, ln1g + l*D_, ln1b + l*D_, hb);
        ggemm_kernel<<<gQKV, dim3(512), 0, stream>>>(hb, wb,
            bq + l*D_, bk + l*D_, bv + l*D_, qb, kb, vb, N_, D_);
        vtr_kernel<<<gVt, blk, 0, stream>>>(vb, vt);
        mattn_kernel<<<gAt, blk, 0, stream>>>(qb, kb, vt, ob);
        dgemm_kernel<0><<<gE64, blk, 0, stream>>>(ob, wb + 3*M1,
            bo + l*D_, x, x, N_, D_);
        ln_kernel<<<N_, blk, 0, stream>>>(x, ln2g + l*D_, ln2b + l*D_, hb);
        dgemm_kernel<1><<<gW1, blk, 0, stream>>>(hb, wb + 4*M1,
            b1 + l*FF_, nullptr, f1, N_, D_);
        dgemm_kernel<0><<<gE64, blk, 0, stream>>>(f1, wb + 4*M1 + M4,
            b2 + l*D_, x, x, N_, FF_);
    }
    gemm_kernel<<<gOut, blk, 0, stream>>>(x, Wout, bout, out, N_, D_, 64);
}